// Round 5
// baseline (718.575 us; speedup 1.0000x reference)
//
#include <hip/hip_runtime.h>

#define BB 2
#define NN 1024
#define N1 1025
#define DM 128
#define NH 8
#define DK 16
#define DFF 512
#define NBUK 32
#define NLAYERS 3
#define KNN_K 10
#define ADJW 17          // 1025 bits -> 17 u64 words per row
#define MW 34            // 34 u32 mask words per row (1088 bits)
#define BSTR 1088        // padded bucket row stride (bytes)
#define NSPLIT 4
#define BIGF 3.0e38f

// prepacked-weight element offsets (see prepack_kernel)
#define PWQ_OFF 0
#define PWK_OFF 49152
#define PWV_OFF 98304
#define PWO_OFF 147456
#define PW1_OFF 196608
#define PW2_OFF 393216
#define PWOUT_OFF 589824
#define PW_TOT 606208

typedef __attribute__((ext_vector_type(8))) short bf8;
typedef __attribute__((ext_vector_type(4))) float f4;
typedef unsigned short u16;
typedef unsigned int u32;

__device__ __forceinline__ u16 f2bf(float x) {
  unsigned u = __float_as_uint(x);
  return (u16)((u + 0x7fff + ((u >> 16) & 1)) >> 16);   // RNE
}
__device__ __forceinline__ float bf2f(u16 u) {
  return __uint_as_float(((unsigned)u) << 16);
}
__device__ __forceinline__ bf8 mk8(ushort4 a, ushort4 b) {
  bf8 r;
  r[0] = (short)a.x; r[1] = (short)a.y; r[2] = (short)a.z; r[3] = (short)a.w;
  r[4] = (short)b.x; r[5] = (short)b.y; r[6] = (short)b.z; r[7] = (short)b.w;
  return r;
}

// ---------------------------------------------------------------- weight prepack
// B-fragment layout: elem((nt,ks,lane,j)) = W[nt*16 + (lane&15)][ks*32 + (lane>>4)*8 + j]
// hi/lo split bf16. One kernel covers all 7 weight tensors (hardcoded segmentation).
__global__ void prepack_kernel(const float* __restrict__ Wq, const float* __restrict__ Wk,
                               const float* __restrict__ Wv, const float* __restrict__ Wo,
                               const float* __restrict__ W1, const float* __restrict__ W2,
                               const float* __restrict__ oW,
                               u16* __restrict__ PH, u16* __restrict__ PL) {
  int idx = blockIdx.x * 256 + threadIdx.x;   // lane-group id (8 elems each)
  if (idx >= 75776) return;
  const float* W; int rel, Kdim;
  if (idx < 24576) {
    int seg = idx / 6144; rel = idx % 6144; Kdim = 128;
    W = seg == 0 ? Wq : seg == 1 ? Wk : seg == 2 ? Wv : Wo;
  } else if (idx < 49152) { rel = idx - 24576; Kdim = 128; W = W1; }
  else if (idx < 73728)   { rel = idx - 49152; Kdim = 512; W = W2; }
  else                    { rel = idx - 73728; Kdim = 128; W = oW; }
  int lane = rel & 63;
  int g = rel >> 6;
  int ksteps = Kdim >> 5;
  int ks = g % ksteps, nt = g / ksteps;
  int n = nt * 16 + (lane & 15);
  int k = ks * 32 + (lane >> 4) * 8;
  const float* p = W + (size_t)n * Kdim + k;
  u16* ph = PH + (size_t)idx * 8;
  u16* pl = PL + (size_t)idx * 8;
  #pragma unroll
  for (int q = 0; q < 8; ++q) {
    float x = p[q];
    u16 hh = f2bf(x);
    ph[q] = hh;
    pl[q] = f2bf(x - bf2f(hh));
  }
}

// ---------------------------------------------------------------- embed
__global__ void embed_kernel(const float* __restrict__ coords, const float* __restrict__ inW,
                             const float* __restrict__ inb, const float* __restrict__ gnode,
                             float* __restrict__ X) {
  int idx = blockIdx.x * 256 + threadIdx.x;
  if (idx >= BB * N1 * DM) return;
  int d = idx % DM; int r = idx / DM; int n = r % N1; int b = r / N1;
  float v;
  if (n < NN) {
    float cx = coords[(b * NN + n) * 2 + 0], cy = coords[(b * NN + n) * 2 + 1];
    v = cx * inW[d * 2 + 0] + cy * inW[d * 2 + 1] + inb[d];
  } else {
    v = gnode[d];
  }
  X[idx] = v;
}

// ---------------------------------------------------------------- bucket (padded rows)
__global__ void bucket_kernel(const float* __restrict__ coords, unsigned char* __restrict__ buckp) {
  int idx = blockIdx.x * 256 + threadIdx.x;
  if (idx >= BB * N1 * BSTR) return;
  int j = idx % BSTR; int r = idx / BSTR; int i = r % N1; int b = r / N1;
  unsigned char v = 0;
  if (j < N1) {
    float xi = 0.f, yi = 0.f, xj = 0.f, yj = 0.f;
    if (i < NN) { xi = coords[(b * NN + i) * 2]; yi = coords[(b * NN + i) * 2 + 1]; }
    if (j < NN) { xj = coords[(b * NN + j) * 2]; yj = coords[(b * NN + j) * 2 + 1]; }
    float dx = xi - xj, dy = yi - yj;
    float dist = sqrtf(dx * dx + dy * dy);
    int bu = (int)(dist * 32.0f);
    bu = bu < 0 ? 0 : (bu > 31 ? 31 : bu);
    v = (unsigned char)bu;
  }
  buckp[idx] = v;
}

// ---------------------------------------------------------------- g += mean(h) (layer 0 only)
__global__ void g_update_kernel(float* __restrict__ X) {
  int d = blockIdx.x; int b = blockIdx.y; int lane = threadIdx.x;  // 64 threads
  float s = 0.f;
  for (int n = lane; n < NN; n += 64) s += X[((size_t)b * N1 + n) * DM + d];
  for (int o = 32; o; o >>= 1) s += __shfl_down(s, o);
  if (lane == 0) X[((size_t)b * N1 + NN) * DM + d] += s * (1.0f / NN);
}

// ---------------------------------------------------------------- row squared norms
__global__ void rowsq_kernel(const float* __restrict__ X, float* __restrict__ sq) {
  int idx = blockIdx.x * 64 + threadIdx.x;
  if (idx >= BB * NN) return;
  int n = idx % NN, b = idx / NN;
  const float* row = X + ((size_t)b * N1 + n) * DM;
  float s = 0.f;
  #pragma unroll 8
  for (int d = 0; d < DM; d += 4) {
    float4 v = *(const float4*)(row + d);
    s += v.x * v.x + v.y * v.y + v.z * v.z + v.w * v.w;
  }
  sq[idx] = s;
}

// ---------------------------------------------------------------- kNN -> adjacency bits
__global__ __launch_bounds__(256) void knn_kernel(const float* __restrict__ X,
                                                  const float* __restrict__ sqb,
                                                  unsigned long long* __restrict__ adj) {
  __shared__ float hi[4][DM];
  __shared__ float dd[4][NN];
  int blk = blockIdx.x;
  int b = blk / (NN / 4);
  int i0 = (blk % (NN / 4)) * 4;
  int t = threadIdx.x;
  int lane = t & 63, w = t >> 6;

  for (int x = t; x < 4 * DM; x += 256)
    hi[x >> 7][x & 127] = X[((size_t)b * N1 + i0 + (x >> 7)) * DM + (x & 127)];
  __syncthreads();

  float sqi0 = sqb[b * NN + i0 + 0];
  float sqi1 = sqb[b * NN + i0 + 1];
  float sqi2 = sqb[b * NN + i0 + 2];
  float sqi3 = sqb[b * NN + i0 + 3];

  for (int j = t; j < NN; j += 256) {
    const float* row = X + ((size_t)b * N1 + j) * DM;
    float d0 = 0.f, d1 = 0.f, d2v = 0.f, d3 = 0.f;
    #pragma unroll 8
    for (int d = 0; d < DM; d += 4) {
      float4 v = *(const float4*)(row + d);
      d0 += hi[0][d] * v.x + hi[0][d + 1] * v.y + hi[0][d + 2] * v.z + hi[0][d + 3] * v.w;
      d1 += hi[1][d] * v.x + hi[1][d + 1] * v.y + hi[1][d + 2] * v.z + hi[1][d + 3] * v.w;
      d2v += hi[2][d] * v.x + hi[2][d + 1] * v.y + hi[2][d + 2] * v.z + hi[2][d + 3] * v.w;
      d3 += hi[3][d] * v.x + hi[3][d + 1] * v.y + hi[3][d + 2] * v.z + hi[3][d + 3] * v.w;
    }
    float sj = sqb[b * NN + j];
    dd[0][j] = (j == i0 + 0) ? BIGF : (sqi0 + sj - 2.f * d0);
    dd[1][j] = (j == i0 + 1) ? BIGF : (sqi1 + sj - 2.f * d1);
    dd[2][j] = (j == i0 + 2) ? BIGF : (sqi2 + sj - 2.f * d2v);
    dd[3][j] = (j == i0 + 3) ? BIGF : (sqi3 + sj - 2.f * d3);
  }
  __syncthreads();

  // phase 2: one wave per query, no block barriers
  int i = i0 + w;
  for (int it = 0; it < KNN_K; ++it) {
    float bv = BIGF; int bi = 0x3fffffff;
    for (int j = lane; j < NN; j += 64) {
      float v = dd[w][j];
      if (v < bv) { bv = v; bi = j; }
    }
    #pragma unroll
    for (int o = 1; o < 64; o <<= 1) {
      float ov = __shfl_xor(bv, o); int oi = __shfl_xor(bi, o);
      if (ov < bv || (ov == bv && oi < bi)) { bv = ov; bi = oi; }
    }
    if (lane == 0) {
      dd[w][bi] = BIGF;
      atomicOr(&adj[((size_t)b * N1 + i) * ADJW + (bi >> 6)], 1ull << (bi & 63));
      atomicOr(&adj[((size_t)b * N1 + bi) * ADJW + (i >> 6)], 1ull << (i & 63));
    }
  }
}

// ---------------------------------------------------------------- conn bitmask build
__global__ void connb_kernel(const unsigned long long* __restrict__ adj,
                             u32* __restrict__ connb) {
  int idx = blockIdx.x * 256 + threadIdx.x;
  if (idx >= BB * N1) return;
  int b = idx / N1, i = idx % N1;
  const u32* arow = (const u32*)(adj + (size_t)(b * N1 + i) * ADJW);
  u32* crow = connb + (size_t)(b * N1 + i) * MW;
  bool allv = (i == 0 || i == NN);
  int lo = 0, hi = -1;
  if (i < NN) {
    int bs = i & ~127;
    lo = i - 11 < bs ? bs : i - 11;
    int be = bs + 127;
    hi = i + 11 > be ? be : i + 11;
  }
  for (int w = 0; w < MW; ++w) {
    u32 v;
    if (allv) {
      v = 0xffffffffu;
    } else {
      v = arow[w];
      int a = lo - 32 * w, bnd = hi - 32 * w;
      if (a < 0) a = 0; if (bnd > 31) bnd = 31;
      if (a <= bnd) v |= (0xffffffffu << a) & (0xffffffffu >> (31 - bnd));
      if (w == 0) v |= 1u;                       // depot col
      if (w == 32) v |= 1u;                      // global col (j=1024)
      int dg = i - 32 * w;
      if (dg >= 0 && dg < 32) v |= 1u << dg;     // diag
    }
    if (w == 32) v &= 1u;
    else if (w == 33) v = 0u;
    crow[w] = v;
  }
}

// ---------------------------------------------------------------- direct-fragment GEMM
// No LDS, no barriers. B from prepacked hi/lo fragments; A converted in-register.
// Wave computes a 16(M) x 64(N) tile; 3 MFMAs per k-step per n-tile (exact split product).
__device__ __forceinline__ void gemm_dev(
    const float* __restrict__ in, const u16* __restrict__ PH, const u16* __restrict__ PL,
    const float* __restrict__ bias, const float* __restrict__ res,
    float* __restrict__ out, int M, int Kdim, int Nout, int relu,
    int mt, int nw) {
  int lane = threadIdx.x & 63;
  int quad = lane >> 4, r16 = lane & 15;
  int ksteps = Kdim >> 5;
  f4 acc[4];
  #pragma unroll
  for (int i = 0; i < 4; ++i) acc[i] = (f4){0.f, 0.f, 0.f, 0.f};

  int m0 = mt * 16;
  int mrow = m0 + r16;
  bool mv = mrow < M;
  const float* ap = in + (size_t)mrow * Kdim + quad * 8;
  const size_t ntstr = (size_t)ksteps * 64 * 8;
  const u16* phb = PH + (size_t)(nw * 4) * ntstr + (size_t)lane * 8;
  const u16* plb = PL + (size_t)(nw * 4) * ntstr + (size_t)lane * 8;

  #pragma unroll 4
  for (int ks = 0; ks < ksteps; ++ks) {
    bf8 aH, aL;
    if (mv) {
      float4 v0 = *(const float4*)(ap);
      float4 v1 = *(const float4*)(ap + 4);
      float av[8] = {v0.x, v0.y, v0.z, v0.w, v1.x, v1.y, v1.z, v1.w};
      #pragma unroll
      for (int q = 0; q < 8; ++q) {
        u16 hh = f2bf(av[q]);
        aH[q] = (short)hh;
        aL[q] = (short)f2bf(av[q] - bf2f(hh));
      }
    } else {
      #pragma unroll
      for (int q = 0; q < 8; ++q) { aH[q] = 0; aL[q] = 0; }
    }
    ap += 32;
    size_t bo = (size_t)ks * 64 * 8;
    #pragma unroll
    for (int nt = 0; nt < 4; ++nt) {
      bf8 bH = *(const bf8*)(phb + nt * ntstr + bo);
      bf8 bL = *(const bf8*)(plb + nt * ntstr + bo);
      acc[nt] = __builtin_amdgcn_mfma_f32_16x16x32_bf16(aH, bH, acc[nt], 0, 0, 0);
      acc[nt] = __builtin_amdgcn_mfma_f32_16x16x32_bf16(aH, bL, acc[nt], 0, 0, 0);
      acc[nt] = __builtin_amdgcn_mfma_f32_16x16x32_bf16(aL, bH, acc[nt], 0, 0, 0);
    }
  }

  if (m0 >= M) return;
  #pragma unroll
  for (int nt = 0; nt < 4; ++nt) {
    int n = nw * 64 + nt * 16 + r16;
    #pragma unroll
    for (int reg = 0; reg < 4; ++reg) {
      int m = m0 + quad * 4 + reg;    // C layout: col=lane&15, row=quad*4+reg
      if (m < M) {
        float v = acc[nt][reg];
        if (bias) v += bias[n];
        if (relu) v = fmaxf(v, 0.f);
        if (res) v += res[(size_t)m * Nout + n];
        out[(size_t)m * Nout + n] = v;
      }
    }
  }
}

__global__ __launch_bounds__(256) void gemm_kernel(
    const float* __restrict__ in, const u16* __restrict__ PH, const u16* __restrict__ PL,
    const float* __restrict__ bias, const float* __restrict__ res,
    float* __restrict__ out, int M, int Kdim, int Nout, int relu) {
  gemm_dev(in, PH, PL, bias, res, out, M, Kdim, Nout, relu,
           blockIdx.x * 4 + (threadIdx.x >> 6), blockIdx.y);
}

__global__ __launch_bounds__(256) void gemm_qkv_kernel(
    const float* __restrict__ in,
    const u16* __restrict__ QH, const u16* __restrict__ QL,
    const u16* __restrict__ KH, const u16* __restrict__ KL,
    const u16* __restrict__ VH, const u16* __restrict__ VL,
    float* __restrict__ Qo, float* __restrict__ Ko, float* __restrict__ Vo, int M) {
  int z = blockIdx.z;
  const u16* PH = z == 0 ? QH : (z == 1 ? KH : VH);
  const u16* PL = z == 0 ? QL : (z == 1 ? KL : VL);
  float* out = z == 0 ? Qo : (z == 1 ? Ko : Vo);
  gemm_dev(in, PH, PL, nullptr, nullptr, out, M, DM, DM, 0,
           blockIdx.x * 4 + (threadIdx.x >> 6), blockIdx.y);
}

// ---------------------------------------------------------------- MFMA flash attention, key-split
// ping-pong LDS: one barrier per chunk; chunk c+1 prefetched to regs during compute of c.
#define CH 64
#define NCH 17
__global__ __launch_bounds__(128) void attn_kernel(
    const float* __restrict__ Q, const float* __restrict__ Kb, const float* __restrict__ Vb,
    const float* __restrict__ emb_l, const unsigned char* __restrict__ buckp,
    const u32* __restrict__ connb, float* __restrict__ Opart,
    float* __restrict__ mpart, float* __restrict__ lpart) {
  __shared__ __align__(16) u16 KsHi[2][CH][20];
  __shared__ __align__(16) u16 KsLo[2][CH][20];
  __shared__ __align__(16) u16 Vt[2][DK][68];
  __shared__ __align__(16) u16 Ps[2][16][72];
  __shared__ float qe_s[2][16][33];
  __shared__ u32 maskS[32][10];
  __shared__ unsigned char buckS[2][32][68];

  int qt = blockIdx.x;                 // 0..32
  int h = blockIdx.y & 7, b = blockIdx.y >> 3;
  int s = blockIdx.z;
  int c0 = (NCH * s) / NSPLIT, c1 = (NCH * (s + 1)) / NSPLIT;
  int nwm = 2 * (c1 - c0);
  int t = threadIdx.x, lane = t & 63, w = t >> 6;
  int quad = lane >> 4, r16 = lane & 15;
  int i0 = qt * 32;
  int iw = i0 + w * 16;
  int bh = b * NH + h;

  // stage this split's mask words for the block's 32 rows
  for (int x = t; x < 32 * nwm; x += 128) {
    int rr = x / nwm, ww = x % nwm;
    int gi = i0 + rr; if (gi > NN) gi = NN;
    maskS[rr][ww] = connb[((size_t)b * N1 + gi) * MW + 2 * c0 + ww];
  }
  // qe table (fp32): wave's 16 rows x 32 buckets
  for (int e = lane; e < 512; e += 64) {
    int rr = e >> 5, bk = e & 31;
    int gi = iw + rr; if (gi > NN) gi = NN;
    const float* qrow = Q + ((size_t)b * N1 + gi) * DM + h * DK;
    const float* er = emb_l + (size_t)bk * DM + h * DK;
    float sum = 0.f;
    #pragma unroll
    for (int d = 0; d < DK; ++d) sum += qrow[d] * er[d];
    qe_s[w][rr][bk] = sum;
  }
  // Q A-fragment: quads 0,1 = hi(0.25*Q), quads 2,3 = lo residual
  bf8 qfrag;
  {
    int gi = iw + r16; if (gi > NN) gi = NN;
    const float* qp = Q + ((size_t)b * N1 + gi) * DM + h * DK + (quad & 1) * 8;
    #pragma unroll
    for (int jj = 0; jj < 8; ++jj) {
      float x = qp[jj] * 0.25f;
      u16 hh = f2bf(x);
      qfrag[jj] = (quad < 2) ? (short)hh : (short)f2bf(x - bf2f(hh));
    }
  }

  float4 kvr[2], vvr[2]; u32 bkr[4];
  auto load_chunk = [&](int c) {
    int j0 = c * CH;
    #pragma unroll
    for (int ii = 0; ii < 2; ++ii) {
      int x = t + ii * 128;
      int key = x >> 2, ds = (x & 3) * 4;
      int jg = j0 + key; if (jg > NN) jg = NN;
      kvr[ii] = *(const float4*)(Kb + ((size_t)b * N1 + jg) * DM + h * DK + ds);
      vvr[ii] = *(const float4*)(Vb + ((size_t)b * N1 + jg) * DM + h * DK + ds);
    }
    #pragma unroll
    for (int ii = 0; ii < 4; ++ii) {
      int x = t + ii * 128;
      int rr = x >> 4, c4 = (x & 15) * 4;
      int gi = i0 + rr; if (gi > NN) gi = NN;
      bkr[ii] = *(const u32*)(buckp + ((size_t)b * N1 + gi) * BSTR + j0 + c4);
    }
  };
  auto store_chunk = [&](int pb) {
    #pragma unroll
    for (int ii = 0; ii < 2; ++ii) {
      int x = t + ii * 128;
      int key = x >> 2, ds = (x & 3) * 4;
      float ka[4] = {kvr[ii].x, kvr[ii].y, kvr[ii].z, kvr[ii].w};
      ushort4 hb, lb; u16* hp = (u16*)&hb; u16* lp = (u16*)&lb;
      #pragma unroll
      for (int q = 0; q < 4; ++q) {
        u16 hh = f2bf(ka[q]);
        hp[q] = hh;
        lp[q] = f2bf(ka[q] - bf2f(hh));
      }
      *(ushort4*)&KsHi[pb][key][ds] = hb;
      *(ushort4*)&KsLo[pb][key][ds] = lb;
      Vt[pb][ds + 0][key] = f2bf(vvr[ii].x);
      Vt[pb][ds + 1][key] = f2bf(vvr[ii].y);
      Vt[pb][ds + 2][key] = f2bf(vvr[ii].z);
      Vt[pb][ds + 3][key] = f2bf(vvr[ii].w);
    }
    #pragma unroll
    for (int ii = 0; ii < 4; ++ii) {
      int x = t + ii * 128;
      int rr = x >> 4, c4 = (x & 15) * 4;
      *(u32*)&buckS[pb][rr][c4] = bkr[ii];
    }
  };

  f4 Oacc = {0.f, 0.f, 0.f, 0.f};
  float mrun[4] = {-1e30f, -1e30f, -1e30f, -1e30f};
  float lrun[4] = {0.f, 0.f, 0.f, 0.f};

  load_chunk(c0);
  store_chunk(0);

  for (int c = c0; c < c1; ++c) {
    int pb = (c - c0) & 1;
    bool pf = (c + 1 < c1);
    if (pf) load_chunk(c + 1);
    __syncthreads();

    // QK^T: 4 tiles of 16 keys, exact product via two MFMAs
    f4 S[4];
    #pragma unroll
    for (int tt = 0; tt < 4; ++tt) {
      int key = tt * 16 + r16;
      int off = (quad & 1) * 8;
      bf8 bhv = mk8(*(const ushort4*)&KsHi[pb][key][off], *(const ushort4*)&KsHi[pb][key][off + 4]);
      bf8 blv = mk8(*(const ushort4*)&KsLo[pb][key][off], *(const ushort4*)&KsLo[pb][key][off + 4]);
      f4 z = {0.f, 0.f, 0.f, 0.f};
      z = __builtin_amdgcn_mfma_f32_16x16x32_bf16(qfrag, bhv, z, 0, 0, 0);
      z = __builtin_amdgcn_mfma_f32_16x16x32_bf16(qfrag, blv, z, 0, 0, 0);
      S[tt] = z;
    }

    // rel + mask + online softmax
    float sv[4][4];
    #pragma unroll
    for (int rg = 0; rg < 4; ++rg) {
      int rowb = w * 16 + quad * 4 + rg;
      u32 mw0 = maskS[rowb][2 * (c - c0)];
      u32 mw1 = maskS[rowb][2 * (c - c0) + 1];
      #pragma unroll
      for (int tt = 0; tt < 4; ++tt) {
        u32 mword = (tt & 2) ? mw1 : mw0;
        int bit = (tt & 1) * 16 + r16;
        int bk = buckS[pb][rowb][tt * 16 + r16] & 31;
        float rel = qe_s[w][quad * 4 + rg][bk];
        float sc = S[tt][rg] + rel;
        sc += ((mword >> bit) & 1u) ? 0.f : -1.0e9f;
        sv[rg][tt] = sc;
      }
    }
    #pragma unroll
    for (int rg = 0; rg < 4; ++rg) {
      float tm = fmaxf(fmaxf(sv[rg][0], sv[rg][1]), fmaxf(sv[rg][2], sv[rg][3]));
      #pragma unroll
      for (int o = 1; o < 16; o <<= 1) tm = fmaxf(tm, __shfl_xor(tm, o));
      float nm = fmaxf(mrun[rg], tm);
      float al = __expf(mrun[rg] - nm);
      mrun[rg] = nm;
      float ps = 0.f;
      #pragma unroll
      for (int tt = 0; tt < 4; ++tt) {
        float p = __expf(sv[rg][tt] - nm);
        ps += p;
        Ps[w][quad * 4 + rg][tt * 16 + r16] = f2bf(p);
      }
      #pragma unroll
      for (int o = 1; o < 16; o <<= 1) ps += __shfl_xor(ps, o);
      lrun[rg] = lrun[rg] * al + ps;
      Oacc[rg] *= al;
    }
    // PV: P (A-layout via wave-local LDS round trip) x V^T
    #pragma unroll
    for (int half = 0; half < 2; ++half) {
      bf8 pa = *(const bf8*)&Ps[w][r16][half * 32 + quad * 8];
      bf8 vb = mk8(*(const ushort4*)&Vt[pb][r16][half * 32 + quad * 8],
                   *(const ushort4*)&Vt[pb][r16][half * 32 + quad * 8 + 4]);
      Oacc = __builtin_amdgcn_mfma_f32_16x16x32_bf16(pa, vb, Oacc, 0, 0, 0);
    }

    if (pf) store_chunk(pb ^ 1);
  }

  // write unnormalized partials
  #pragma unroll
  for (int rg = 0; rg < 4; ++rg) {
    int gi = i0 + w * 16 + quad * 4 + rg;
    if (gi < N1) {
      size_t base = ((size_t)(bh * NSPLIT + s) * N1 + gi);
      Opart[base * 16 + r16] = Oacc[rg];
      if (r16 == 0) {
        mpart[base] = mrun[rg];
        lpart[base] = lrun[rg];
      }
    }
  }
}

// ---------------------------------------------------------------- combine split partials (exact fp32)
__global__ void attn_combine_kernel(const float* __restrict__ Opart,
                                    const float* __restrict__ mpart,
                                    const float* __restrict__ lpart,
                                    float* __restrict__ ctx) {
  int idx = blockIdx.x * 256 + threadIdx.x;
  if (idx >= BB * NH * N1) return;
  int q = idx % N1; int bh = idx / N1; int h = bh & 7; int b = bh >> 3;
  float ms[NSPLIT];
  float m = -BIGF;
  #pragma unroll
  for (int s = 0; s < NSPLIT; ++s) {
    ms[s] = mpart[(size_t)(bh * NSPLIT + s) * N1 + q];
    m = fmaxf(m, ms[s]);
  }
  float l = 0.f;
  float o[16];
  #pragma unroll
  for (int d = 0; d < DK; ++d) o[d] = 0.f;
  #pragma unroll
  for (int s = 0; s < NSPLIT; ++s) {
    float wgt = __expf(ms[s] - m);
    size_t base = (size_t)(bh * NSPLIT + s) * N1 + q;
    l += lpart[base] * wgt;
    const float* op = Opart + base * 16;
    #pragma unroll
    for (int d = 0; d < DK; ++d) o[d] += op[d] * wgt;
  }
  float inv = 1.0f / l;
  float* orow = ctx + ((size_t)b * N1 + q) * DM + h * DK;
  #pragma unroll
  for (int d = 0; d < DK; ++d) orow[d] = o[d] * inv;
}

// ---------------------------------------------------------------- instance norm (+pool, +g-update)
__global__ void inorm_kernel(float* __restrict__ X, const float* __restrict__ w,
                             const float* __restrict__ b_, float* __restrict__ pool,
                             int do_g) {
  int d = blockIdx.x; int bb = blockIdx.y; int lane = threadIdx.x;  // 64 threads
  float g_old = X[((size_t)bb * N1 + NN) * DM + d];
  float s = 0.f;
  for (int n = lane; n < N1; n += 64) s += X[((size_t)bb * N1 + n) * DM + d];
  #pragma unroll
  for (int o = 1; o < 64; o <<= 1) s += __shfl_xor(s, o);
  float mu = s * (1.0f / N1);
  float v = 0.f;
  for (int n = lane; n < N1; n += 64) {
    float tt = X[((size_t)bb * N1 + n) * DM + d] - mu;
    v += tt * tt;
  }
  #pragma unroll
  for (int o = 1; o < 64; o <<= 1) v += __shfl_xor(v, o);
  float var = v * (1.0f / N1);
  float scv = rsqrtf(var + 1e-5f) * w[d];
  float sh = b_[d];
  for (int n = lane; n < N1; n += 64) {
    size_t id = ((size_t)bb * N1 + n) * DM + d;
    X[id] = (X[id] - mu) * scv + sh;
  }
  if (lane == 0) {
    float hmean = ((s - g_old) * (1.0f / NN) - mu) * scv + sh;
    if (pool) pool[bb * DM + d] = hmean;
    if (do_g) X[((size_t)bb * N1 + NN) * DM + d] += hmean;
  }
}

// ---------------------------------------------------------------- p_multi + (h + pm) fused
__global__ void pmadd_kernel(const float* __restrict__ X, const float* __restrict__ pools,
                             float* __restrict__ out_pm, float* __restrict__ tmp2) {
  int idx = blockIdx.x * 256 + threadIdx.x;
  if (idx >= BB * NN * DM) return;
  int d = idx % DM; int n = (idx / DM) % NN; int b = idx / (DM * NN);
  int pd = b * DM + d;
  float pmv = (pools[pd] + pools[BB * DM + pd] + pools[2 * BB * DM + pd]) * (1.0f / 3.0f);
  tmp2[idx] = X[((size_t)b * N1 + n) * DM + d] + pmv;
  if (n == 0) out_pm[pd] = pmv;
}

// ================================================================ launch
extern "C" void kernel_launch(void* const* d_in, const int* in_sizes, int n_in,
                              void* d_out, int out_size, void* d_ws, size_t ws_size,
                              hipStream_t stream) {
  const float* coords = (const float*)d_in[0];
  const float* inW    = (const float*)d_in[1];
  const float* inb    = (const float*)d_in[2];
  const float* gnode  = (const float*)d_in[3];
  const float* Wq     = (const float*)d_in[4];
  const float* Wk     = (const float*)d_in[5];
  const float* Wv     = (const float*)d_in[6];
  const float* Wo     = (const float*)d_in[7];
  const float* emb    = (const float*)d_in[8];
  const float* W1     = (const float*)d_in[9];
  const float* b1     = (const float*)d_in[10];
  const float* W2     = (const float*)d_in[11];
  const float* b2     = (const float*)d_in[12];
  const float* n1w    = (const float*)d_in[13];
  const float* n1b    = (const float*)d_in[14];
  const float* n2w    = (const float*)d_in[15];
  const float* n2b    = (const float*)d_in[16];
  const float* outW   = (const float*)d_in[17];
  const float* outb   = (const float*)d_in[18];
  float* out = (float*)d_out;

  char* wsp = (char*)d_ws;
  size_t off = 0;
  auto alloc = [&](size_t bytes) -> void* {
    off = (off + 255) & ~(size_t)255;
    void* p = wsp + off;
    off += bytes;
    return p;
  };
  const size_t XB = (size_t)BB * N1 * DM * 4;
  float* X0   = (float*)alloc(XB);
  float* X1   = (float*)alloc(XB);
  float* Qb   = (float*)alloc(XB);
  float* Kbuf = (float*)alloc(XB);
  float* Vbuf = (float*)alloc(XB);
  float* Cb   = (float*)alloc(XB);
  float* Yb   = (float*)alloc(XB);
  float* Fb   = (float*)alloc((size_t)BB * N1 * DFF * 4);   // also attn Opart (disjoint in time)
  unsigned char* buckp = (unsigned char*)alloc((size_t)BB * N1 * BSTR);
  unsigned long long* adj = (unsigned long long*)alloc((size_t)BB * N1 * ADJW * 8);
  u32* connb = (u32*)alloc((size_t)BB * N1 * MW * 4);
  float* sqb   = (float*)alloc((size_t)BB * NN * 4);
  float* pools = (float*)alloc((size_t)NLAYERS * BB * DM * 4);
  float* tmp   = (float*)alloc((size_t)BB * NN * DM * 4);   // also attn m/l partials
  u16* PH = (u16*)alloc((size_t)PW_TOT * 2);
  u16* PL = (u16*)alloc((size_t)PW_TOT * 2);

  float* Opart = Fb;
  float* mpart = tmp;
  float* lpart = tmp + 65600;

  prepack_kernel<<<296, 256, 0, stream>>>(Wq, Wk, Wv, Wo, W1, W2, outW, PH, PL);
  embed_kernel<<<(BB * N1 * DM + 255) / 256, 256, 0, stream>>>(coords, inW, inb, gnode, X0);
  bucket_kernel<<<(BB * N1 * BSTR + 255) / 256, 256, 0, stream>>>(coords, buckp);
  g_update_kernel<<<dim3(DM, BB), 64, 0, stream>>>(X0);   // layer 0 g-update

  float* Xin = X0; float* Xout = X1;
  const int M = BB * N1;
  const int GX = 33;     // ceil(ceil(2050/16)/4)
  for (int l = 0; l < NLAYERS; ++l) {
    hipMemsetAsync(adj, 0, (size_t)BB * N1 * ADJW * 8, stream);
    rowsq_kernel<<<(BB * NN + 63) / 64, 64, 0, stream>>>(Xin, sqb);
    knn_kernel<<<BB * NN / 4, 256, 0, stream>>>(Xin, sqb, adj);
    connb_kernel<<<(BB * N1 + 255) / 256, 256, 0, stream>>>(adj, connb);

    gemm_qkv_kernel<<<dim3(GX, 2, 3), 256, 0, stream>>>(
        Xin,
        PH + PWQ_OFF + (size_t)l * DM * DM, PL + PWQ_OFF + (size_t)l * DM * DM,
        PH + PWK_OFF + (size_t)l * DM * DM, PL + PWK_OFF + (size_t)l * DM * DM,
        PH + PWV_OFF + (size_t)l * DM * DM, PL + PWV_OFF + (size_t)l * DM * DM,
        Qb, Kbuf, Vbuf, M);

    attn_kernel<<<dim3(33, NH * BB, NSPLIT), 128, 0, stream>>>(
        Qb, Kbuf, Vbuf, emb + (size_t)l * NBUK * DM, buckp, connb, Opart, mpart, lpart);
    attn_combine_kernel<<<(BB * NH * N1 + 255) / 256, 256, 0, stream>>>(
        Opart, mpart, lpart, Cb);

    gemm_kernel<<<dim3(GX, 2), 256, 0, stream>>>(
        Cb, PH + PWO_OFF + (size_t)l * DM * DM, PL + PWO_OFF + (size_t)l * DM * DM,
        nullptr, Xin, Yb, M, DM, DM, 0);
    inorm_kernel<<<dim3(DM, BB), 64, 0, stream>>>(Yb, n1w + l * DM, n1b + l * DM, nullptr, 0);

    gemm_kernel<<<dim3(GX, 8), 256, 0, stream>>>(
        Yb, PH + PW1_OFF + (size_t)l * DFF * DM, PL + PW1_OFF + (size_t)l * DFF * DM,
        b1 + l * DFF, nullptr, Fb, M, DM, DFF, 1);
    gemm_kernel<<<dim3(GX, 2), 256, 0, stream>>>(
        Fb, PH + PW2_OFF + (size_t)l * DM * DFF, PL + PW2_OFF + (size_t)l * DM * DFF,
        b2 + l * DM, Yb, Xout, M, DFF, DM, 0);
    inorm_kernel<<<dim3(DM, BB), 64, 0, stream>>>(Xout, n2w + l * DM, n2b + l * DM,
                                                  pools + (size_t)l * BB * DM, 1);

    float* t2 = Xin; Xin = Xout; Xout = t2;
  }

  pmadd_kernel<<<(BB * NN * DM + 255) / 256, 256, 0, stream>>>(
      Xin, pools, out + (size_t)BB * NN * DM, tmp);
  gemm_kernel<<<dim3(32, 2), 256, 0, stream>>>(
      tmp, PH + PWOUT_OFF, PL + PWOUT_OFF, outb, nullptr, out, BB * NN, DM, DM, 0);
}

// Round 7
// 589.988 us; speedup vs baseline: 1.2179x; 1.2179x over previous
//
#include <hip/hip_runtime.h>

#define BB 2
#define NN 1024
#define N1 1025
#define DM 128
#define NH 8
#define DK 16
#define DFF 512
#define NBUK 32
#define NLAYERS 3
#define KNN_K 10
#define ADJW 17          // 1025 bits -> 17 u64 words per row
#define MW 34            // 34 u32 mask words per row (1088 bits)
#define BSTR 1088        // padded bucket row stride (bytes)
#define NSPLIT 4
#define BIGF 3.0e38f

// prepacked-weight element offsets (see prepack_kernel)
#define PWQ_OFF 0
#define PWK_OFF 49152
#define PWV_OFF 98304
#define PWO_OFF 147456
#define PW1_OFF 196608
#define PW2_OFF 393216
#define PWOUT_OFF 589824
#define PW_TOT 606208

typedef __attribute__((ext_vector_type(8))) short bf8;
typedef __attribute__((ext_vector_type(4))) float f4;
typedef unsigned short u16;
typedef unsigned int u32;

__device__ __forceinline__ u16 f2bf(float x) {
  unsigned u = __float_as_uint(x);
  return (u16)((u + 0x7fff + ((u >> 16) & 1)) >> 16);   // RNE
}
__device__ __forceinline__ float bf2f(u16 u) {
  return __uint_as_float(((unsigned)u) << 16);
}
__device__ __forceinline__ bf8 mk8(ushort4 a, ushort4 b) {
  bf8 r;
  r[0] = (short)a.x; r[1] = (short)a.y; r[2] = (short)a.z; r[3] = (short)a.w;
  r[4] = (short)b.x; r[5] = (short)b.y; r[6] = (short)b.z; r[7] = (short)b.w;
  return r;
}

// ---------------------------------------------------------------- weight prepack
// B-fragment layout: elem((nt,ks,lane,j)) = W[nt*16 + (lane&15)][ks*32 + (lane>>4)*8 + j]
__global__ void prepack_kernel(const float* __restrict__ Wq, const float* __restrict__ Wk,
                               const float* __restrict__ Wv, const float* __restrict__ Wo,
                               const float* __restrict__ W1, const float* __restrict__ W2,
                               const float* __restrict__ oW,
                               u16* __restrict__ PH, u16* __restrict__ PL) {
  int idx = blockIdx.x * 256 + threadIdx.x;   // lane-group id (8 elems each)
  if (idx >= 75776) return;
  const float* W; int rel, Kdim;
  if (idx < 24576) {
    int seg = idx / 6144; rel = idx % 6144; Kdim = 128;
    W = seg == 0 ? Wq : seg == 1 ? Wk : seg == 2 ? Wv : Wo;
  } else if (idx < 49152) { rel = idx - 24576; Kdim = 128; W = W1; }
  else if (idx < 73728)   { rel = idx - 49152; Kdim = 512; W = W2; }
  else                    { rel = idx - 73728; Kdim = 128; W = oW; }
  int lane = rel & 63;
  int g = rel >> 6;
  int ksteps = Kdim >> 5;
  int ks = g % ksteps, nt = g / ksteps;
  int n = nt * 16 + (lane & 15);
  int k = ks * 32 + (lane >> 4) * 8;
  const float* p = W + (size_t)n * Kdim + k;
  u16* ph = PH + (size_t)idx * 8;
  u16* pl = PL + (size_t)idx * 8;
  #pragma unroll
  for (int q = 0; q < 8; ++q) {
    float x = p[q];
    u16 hh = f2bf(x);
    ph[q] = hh;
    pl[q] = f2bf(x - bf2f(hh));
  }
}

// ---------------------------------------------------------------- embed
__global__ void embed_kernel(const float* __restrict__ coords, const float* __restrict__ inW,
                             const float* __restrict__ inb, const float* __restrict__ gnode,
                             float* __restrict__ X) {
  int idx = blockIdx.x * 256 + threadIdx.x;
  if (idx >= BB * N1 * DM) return;
  int d = idx % DM; int r = idx / DM; int n = r % N1; int b = r / N1;
  float v;
  if (n < NN) {
    float cx = coords[(b * NN + n) * 2 + 0], cy = coords[(b * NN + n) * 2 + 1];
    v = cx * inW[d * 2 + 0] + cy * inW[d * 2 + 1] + inb[d];
  } else {
    v = gnode[d];
  }
  X[idx] = v;
}

// ---------------------------------------------------------------- bucket (padded rows)
__global__ void bucket_kernel(const float* __restrict__ coords, unsigned char* __restrict__ buckp) {
  int idx = blockIdx.x * 256 + threadIdx.x;
  if (idx >= BB * N1 * BSTR) return;
  int j = idx % BSTR; int r = idx / BSTR; int i = r % N1; int b = r / N1;
  unsigned char v = 0;
  if (j < N1) {
    float xi = 0.f, yi = 0.f, xj = 0.f, yj = 0.f;
    if (i < NN) { xi = coords[(b * NN + i) * 2]; yi = coords[(b * NN + i) * 2 + 1]; }
    if (j < NN) { xj = coords[(b * NN + j) * 2]; yj = coords[(b * NN + j) * 2 + 1]; }
    float dx = xi - xj, dy = yi - yj;
    float dist = sqrtf(dx * dx + dy * dy);
    int bu = (int)(dist * 32.0f);
    bu = bu < 0 ? 0 : (bu > 31 ? 31 : bu);
    v = (unsigned char)bu;
  }
  buckp[idx] = v;
}

// ---------------------------------------------------------------- g += mean(h) (layer 0 only)
__global__ void g_update_kernel(float* __restrict__ X) {
  int d = blockIdx.x; int b = blockIdx.y; int lane = threadIdx.x;  // 64 threads
  float s = 0.f;
  for (int n = lane; n < NN; n += 64) s += X[((size_t)b * N1 + n) * DM + d];
  for (int o = 32; o; o >>= 1) s += __shfl_down(s, o);
  if (lane == 0) X[((size_t)b * N1 + NN) * DM + d] += s * (1.0f / NN);
}

// ---------------------------------------------------------------- row squared norms
__global__ void rowsq_kernel(const float* __restrict__ X, float* __restrict__ sq) {
  int idx = blockIdx.x * 64 + threadIdx.x;
  if (idx >= BB * NN) return;
  int n = idx % NN, b = idx / NN;
  const float* row = X + ((size_t)b * N1 + n) * DM;
  float s = 0.f;
  #pragma unroll 8
  for (int d = 0; d < DM; d += 4) {
    float4 v = *(const float4*)(row + d);
    s += v.x * v.x + v.y * v.y + v.z * v.z + v.w * v.w;
  }
  sq[idx] = s;
}

// ---------------------------------------------------------------- exact MFMA gram: d2 = si + sj - 2*X.X^T
// 3-level bf16 split (H+M+L == x exactly in fp32); per 16-k step 3 MFMAs capture all
// product terms >= 2^-27 rel. Error class == fp32 VALU chain (R4-proven for kNN rank).
__global__ __launch_bounds__(256) void gram_kernel(
    const float* __restrict__ X, const float* __restrict__ sqb,
    float* __restrict__ d2) {
  __shared__ __align__(16) u16 AsH[32][72];
  __shared__ __align__(16) u16 AsM[32][72];
  __shared__ __align__(16) u16 AsL[32][72];
  __shared__ __align__(16) u16 BsH[64][72];
  __shared__ __align__(16) u16 BsM[64][72];
  __shared__ __align__(16) u16 BsL[64][72];
  int b = blockIdx.z;
  int m0 = blockIdx.x * 32, n0 = blockIdx.y * 64;
  const float* Xb = X + (size_t)b * N1 * DM;
  int t = threadIdx.x;
  int lane = t & 63, w = t >> 6;
  int wm = (w >> 1) * 16, wn = (w & 1) * 32;
  int quad = lane >> 4, r16 = lane & 15;

  f4 acc0 = {0.f, 0.f, 0.f, 0.f}, acc1 = {0.f, 0.f, 0.f, 0.f};
  int ar = t >> 3, as_ = (t & 7) * 8;     // A: 32 rows x 8 segs of 8
  int br = t >> 2, bs_ = (t & 3) * 16;    // B: 64 rows x 4 segs of 16

  for (int k0 = 0; k0 < DM; k0 += 64) {
    {
      const float* p = Xb + (size_t)(m0 + ar) * DM + k0 + as_;
      bf8 hb, mb, lb;
      #pragma unroll
      for (int q = 0; q < 8; ++q) {
        float x = p[q];
        u16 hh = f2bf(x); float r1 = x - bf2f(hh);
        u16 mm = f2bf(r1); float r2 = r1 - bf2f(mm);
        hb[q] = (short)hh; mb[q] = (short)mm; lb[q] = (short)f2bf(r2);
      }
      *(bf8*)&AsH[ar][as_] = hb;
      *(bf8*)&AsM[ar][as_] = mb;
      *(bf8*)&AsL[ar][as_] = lb;
    }
    {
      const float* p = Xb + (size_t)(n0 + br) * DM + k0 + bs_;
      #pragma unroll
      for (int seg = 0; seg < 2; ++seg) {
        bf8 hb, mb, lb;
        #pragma unroll
        for (int q = 0; q < 8; ++q) {
          float x = p[seg * 8 + q];
          u16 hh = f2bf(x); float r1 = x - bf2f(hh);
          u16 mm = f2bf(r1); float r2 = r1 - bf2f(mm);
          hb[q] = (short)hh; mb[q] = (short)mm; lb[q] = (short)f2bf(r2);
        }
        *(bf8*)&BsH[br][bs_ + seg * 8] = hb;
        *(bf8*)&BsM[br][bs_ + seg * 8] = mb;
        *(bf8*)&BsL[br][bs_ + seg * 8] = lb;
      }
    }
    __syncthreads();
    #pragma unroll
    for (int ks = 0; ks < 64; ks += 16) {
      int seg = (quad & 1) * 8;
      // A frags: quads 0,1 = H; quads 2,3 = M (resp. L)
      bf8 aHM = *(const bf8*)((quad < 2) ? &AsH[wm + r16][ks + seg] : &AsM[wm + r16][ks + seg]);
      bf8 aHL = *(const bf8*)((quad < 2) ? &AsH[wm + r16][ks + seg] : &AsL[wm + r16][ks + seg]);
      #pragma unroll
      for (int tt = 0; tt < 2; ++tt) {
        int nr = wn + tt * 16 + r16;
        bf8 bH = *(const bf8*)&BsH[nr][ks + seg];
        bf8 bM = *(const bf8*)&BsM[nr][ks + seg];
        bf8 b3 = *(const bf8*)((quad < 2) ? &BsL[nr][ks + seg] : &BsH[nr][ks + seg]);
        f4& a = tt ? acc1 : acc0;
        a = __builtin_amdgcn_mfma_f32_16x16x32_bf16(aHM, bH, a, 0, 0, 0);  // HH' + MH'
        a = __builtin_amdgcn_mfma_f32_16x16x32_bf16(aHM, bM, a, 0, 0, 0);  // HM' + MM'
        a = __builtin_amdgcn_mfma_f32_16x16x32_bf16(aHL, b3, a, 0, 0, 0);  // HL' + LH'
      }
    }
    __syncthreads();
  }

  #pragma unroll
  for (int tt = 0; tt < 2; ++tt) {
    f4 a = tt ? acc1 : acc0;
    int n = n0 + wn + tt * 16 + r16;
    float sj = sqb[b * NN + n];
    #pragma unroll
    for (int reg = 0; reg < 4; ++reg) {
      int m = m0 + wm + quad * 4 + reg;
      float si = sqb[b * NN + m];
      float v = (m == n) ? BIGF : (si + sj - 2.f * a[reg]);
      d2[((size_t)b * NN + m) * NN + n] = v;
    }
  }
}

// ---------------------------------------------------------------- top-10 select -> adjacency bits
__global__ __launch_bounds__(256) void knnsel_kernel(const float* __restrict__ d2,
                                                     unsigned long long* __restrict__ adj) {
  __shared__ float dd[4][NN];
  int blk = blockIdx.x;
  int b = blk / (NN / 4);
  int i0 = (blk % (NN / 4)) * 4;
  int t = threadIdx.x, lane = t & 63, w = t >> 6;

  const float4* src = (const float4*)(d2 + ((size_t)b * NN + i0) * NN);
  float4* dst = (float4*)&dd[0][0];
  #pragma unroll
  for (int x = 0; x < 4; ++x) dst[t + x * 256] = src[t + x * 256];
  __syncthreads();

  int i = i0 + w;
  for (int it = 0; it < KNN_K; ++it) {
    float bv = BIGF; int bi = 0x3fffffff;
    for (int j = lane; j < NN; j += 64) {
      float v = dd[w][j];
      if (v < bv) { bv = v; bi = j; }
    }
    #pragma unroll
    for (int o = 1; o < 64; o <<= 1) {
      float ov = __shfl_xor(bv, o); int oi = __shfl_xor(bi, o);
      if (ov < bv || (ov == bv && oi < bi)) { bv = ov; bi = oi; }
    }
    if (lane == 0) {
      dd[w][bi] = BIGF;
      atomicOr(&adj[((size_t)b * N1 + i) * ADJW + (bi >> 6)], 1ull << (bi & 63));
      atomicOr(&adj[((size_t)b * N1 + bi) * ADJW + (i >> 6)], 1ull << (i & 63));
    }
  }
}

// ---------------------------------------------------------------- conn bitmask build
__global__ void connb_kernel(const unsigned long long* __restrict__ adj,
                             u32* __restrict__ connb) {
  int idx = blockIdx.x * 256 + threadIdx.x;
  if (idx >= BB * N1) return;
  int b = idx / N1, i = idx % N1;
  const u32* arow = (const u32*)(adj + (size_t)(b * N1 + i) * ADJW);
  u32* crow = connb + (size_t)(b * N1 + i) * MW;
  bool allv = (i == 0 || i == NN);
  int lo = 0, hi = -1;
  if (i < NN) {
    int bs = i & ~127;
    lo = i - 11 < bs ? bs : i - 11;
    int be = bs + 127;
    hi = i + 11 > be ? be : i + 11;
  }
  for (int w = 0; w < MW; ++w) {
    u32 v;
    if (allv) {
      v = 0xffffffffu;
    } else {
      v = arow[w];
      int a = lo - 32 * w, bnd = hi - 32 * w;
      if (a < 0) a = 0; if (bnd > 31) bnd = 31;
      if (a <= bnd) v |= (0xffffffffu << a) & (0xffffffffu >> (31 - bnd));
      if (w == 0) v |= 1u;
      if (w == 32) v |= 1u;
      int dg = i - 32 * w;
      if (dg >= 0 && dg < 32) v |= 1u << dg;
    }
    if (w == 32) v &= 1u;
    else if (w == 33) v = 0u;
    crow[w] = v;
  }
}

// ---------------------------------------------------------------- direct-fragment GEMM (16x16/wave)
// No LDS, no barriers. One 16(M)x16(N) tile per wave -> max TLP for skinny GEMMs.
__device__ __forceinline__ void gemm_dev16(
    const float* __restrict__ in, const u16* __restrict__ PH, const u16* __restrict__ PL,
    const float* __restrict__ bias, const float* __restrict__ res,
    float* __restrict__ out, int M, int Kdim, int Nout, int relu,
    int mt, int nt) {
  int lane = threadIdx.x & 63;
  int quad = lane >> 4, r16 = lane & 15;
  int ksteps = Kdim >> 5;
  f4 acc = {0.f, 0.f, 0.f, 0.f};

  int m0 = mt * 16;
  int mrow = m0 + r16;
  bool mv = mrow < M;
  const float* ap = in + (size_t)mrow * Kdim + quad * 8;
  const u16* ph = PH + ((size_t)nt * ksteps * 64 + lane) * 8;
  const u16* pl = PL + ((size_t)nt * ksteps * 64 + lane) * 8;

  #pragma unroll 4
  for (int ks = 0; ks < ksteps; ++ks) {
    bf8 aH, aL;
    if (mv) {
      float4 v0 = *(const float4*)(ap);
      float4 v1 = *(const float4*)(ap + 4);
      float av[8] = {v0.x, v0.y, v0.z, v0.w, v1.x, v1.y, v1.z, v1.w};
      #pragma unroll
      for (int q = 0; q < 8; ++q) {
        u16 hh = f2bf(av[q]);
        aH[q] = (short)hh;
        aL[q] = (short)f2bf(av[q] - bf2f(hh));
      }
    } else {
      #pragma unroll
      for (int q = 0; q < 8; ++q) { aH[q] = 0; aL[q] = 0; }
    }
    ap += 32;
    bf8 bH = *(const bf8*)(ph + (size_t)ks * 512);
    bf8 bL = *(const bf8*)(pl + (size_t)ks * 512);
    acc = __builtin_amdgcn_mfma_f32_16x16x32_bf16(aH, bH, acc, 0, 0, 0);
    acc = __builtin_amdgcn_mfma_f32_16x16x32_bf16(aH, bL, acc, 0, 0, 0);
    acc = __builtin_amdgcn_mfma_f32_16x16x32_bf16(aL, bH, acc, 0, 0, 0);
  }

  if (m0 >= M) return;
  int n = nt * 16 + r16;
  #pragma unroll
  for (int reg = 0; reg < 4; ++reg) {
    int m = m0 + quad * 4 + reg;    // C layout: col=lane&15, row=quad*4+reg
    if (m < M) {
      float v = acc[reg];
      if (bias) v += bias[n];
      if (relu) v = fmaxf(v, 0.f);
      if (res) v += res[(size_t)m * Nout + n];
      out[(size_t)m * Nout + n] = v;
    }
  }
}

__global__ __launch_bounds__(256) void gemm_kernel(
    const float* __restrict__ in, const u16* __restrict__ PH, const u16* __restrict__ PL,
    const float* __restrict__ bias, const float* __restrict__ res,
    float* __restrict__ out, int M, int Kdim, int Nout, int relu) {
  gemm_dev16(in, PH, PL, bias, res, out, M, Kdim, Nout, relu,
             blockIdx.x * 4 + (threadIdx.x >> 6), blockIdx.y);
}

__global__ __launch_bounds__(256) void gemm_qkv_kernel(
    const float* __restrict__ in,
    const u16* __restrict__ QH, const u16* __restrict__ QL,
    const u16* __restrict__ KH, const u16* __restrict__ KL,
    const u16* __restrict__ VH, const u16* __restrict__ VL,
    float* __restrict__ Qo, float* __restrict__ Ko, float* __restrict__ Vo, int M) {
  int z = blockIdx.z;
  const u16* PH = z == 0 ? QH : (z == 1 ? KH : VH);
  const u16* PL = z == 0 ? QL : (z == 1 ? KL : VL);
  float* out = z == 0 ? Qo : (z == 1 ? Ko : Vo);
  gemm_dev16(in, PH, PL, nullptr, nullptr, out, M, DM, DM, 0,
             blockIdx.x * 4 + (threadIdx.x >> 6), blockIdx.y);
}

// ---------------------------------------------------------------- MFMA flash attention, key-split
#define CH 64
#define NCH 17
__global__ __launch_bounds__(128) void attn_kernel(
    const float* __restrict__ Q, const float* __restrict__ Kb, const float* __restrict__ Vb,
    const float* __restrict__ emb_l, const unsigned char* __restrict__ buckp,
    const u32* __restrict__ connb, float* __restrict__ Opart,
    float* __restrict__ mpart, float* __restrict__ lpart) {
  __shared__ __align__(16) u16 KsHi[2][CH][20];
  __shared__ __align__(16) u16 KsLo[2][CH][20];
  __shared__ __align__(16) u16 Vt[2][DK][68];
  __shared__ __align__(16) u16 Ps[2][16][72];
  __shared__ float qe_s[2][16][33];
  __shared__ u32 maskS[32][10];
  __shared__ unsigned char buckS[2][32][68];

  int qt = blockIdx.x;
  int h = blockIdx.y & 7, b = blockIdx.y >> 3;
  int s = blockIdx.z;
  int c0 = (NCH * s) / NSPLIT, c1 = (NCH * (s + 1)) / NSPLIT;
  int nwm = 2 * (c1 - c0);
  int t = threadIdx.x, lane = t & 63, w = t >> 6;
  int quad = lane >> 4, r16 = lane & 15;
  int i0 = qt * 32;
  int iw = i0 + w * 16;
  int bh = b * NH + h;

  for (int x = t; x < 32 * nwm; x += 128) {
    int rr = x / nwm, ww = x % nwm;
    int gi = i0 + rr; if (gi > NN) gi = NN;
    maskS[rr][ww] = connb[((size_t)b * N1 + gi) * MW + 2 * c0 + ww];
  }
  for (int e = lane; e < 512; e += 64) {
    int rr = e >> 5, bk = e & 31;
    int gi = iw + rr; if (gi > NN) gi = NN;
    const float* qrow = Q + ((size_t)b * N1 + gi) * DM + h * DK;
    const float* er = emb_l + (size_t)bk * DM + h * DK;
    float sum = 0.f;
    #pragma unroll
    for (int d = 0; d < DK; ++d) sum += qrow[d] * er[d];
    qe_s[w][rr][bk] = sum;
  }
  bf8 qfrag;
  {
    int gi = iw + r16; if (gi > NN) gi = NN;
    const float* qp = Q + ((size_t)b * N1 + gi) * DM + h * DK + (quad & 1) * 8;
    #pragma unroll
    for (int jj = 0; jj < 8; ++jj) {
      float x = qp[jj] * 0.25f;
      u16 hh = f2bf(x);
      qfrag[jj] = (quad < 2) ? (short)hh : (short)f2bf(x - bf2f(hh));
    }
  }

  float4 kvr[2], vvr[2]; u32 bkr[4];
  auto load_chunk = [&](int c) {
    int j0 = c * CH;
    #pragma unroll
    for (int ii = 0; ii < 2; ++ii) {
      int x = t + ii * 128;
      int key = x >> 2, ds = (x & 3) * 4;
      int jg = j0 + key; if (jg > NN) jg = NN;
      kvr[ii] = *(const float4*)(Kb + ((size_t)b * N1 + jg) * DM + h * DK + ds);
      vvr[ii] = *(const float4*)(Vb + ((size_t)b * N1 + jg) * DM + h * DK + ds);
    }
    #pragma unroll
    for (int ii = 0; ii < 4; ++ii) {
      int x = t + ii * 128;
      int rr = x >> 4, c4 = (x & 15) * 4;
      int gi = i0 + rr; if (gi > NN) gi = NN;
      bkr[ii] = *(const u32*)(buckp + ((size_t)b * N1 + gi) * BSTR + j0 + c4);
    }
  };
  auto store_chunk = [&](int pb) {
    #pragma unroll
    for (int ii = 0; ii < 2; ++ii) {
      int x = t + ii * 128;
      int key = x >> 2, ds = (x & 3) * 4;
      float ka[4] = {kvr[ii].x, kvr[ii].y, kvr[ii].z, kvr[ii].w};
      ushort4 hb, lb; u16* hp = (u16*)&hb; u16* lp = (u16*)&lb;
      #pragma unroll
      for (int q = 0; q < 4; ++q) {
        u16 hh = f2bf(ka[q]);
        hp[q] = hh;
        lp[q] = f2bf(ka[q] - bf2f(hh));
      }
      *(ushort4*)&KsHi[pb][key][ds] = hb;
      *(ushort4*)&KsLo[pb][key][ds] = lb;
      Vt[pb][ds + 0][key] = f2bf(vvr[ii].x);
      Vt[pb][ds + 1][key] = f2bf(vvr[ii].y);
      Vt[pb][ds + 2][key] = f2bf(vvr[ii].z);
      Vt[pb][ds + 3][key] = f2bf(vvr[ii].w);
    }
    #pragma unroll
    for (int ii = 0; ii < 4; ++ii) {
      int x = t + ii * 128;
      int rr = x >> 4, c4 = (x & 15) * 4;
      *(u32*)&buckS[pb][rr][c4] = bkr[ii];
    }
  };

  f4 Oacc = {0.f, 0.f, 0.f, 0.f};
  float mrun[4] = {-1e30f, -1e30f, -1e30f, -1e30f};
  float lrun[4] = {0.f, 0.f, 0.f, 0.f};

  load_chunk(c0);
  store_chunk(0);

  for (int c = c0; c < c1; ++c) {
    int pb = (c - c0) & 1;
    bool pf = (c + 1 < c1);
    if (pf) load_chunk(c + 1);
    __syncthreads();

    f4 S[4];
    #pragma unroll
    for (int tt = 0; tt < 4; ++tt) {
      int key = tt * 16 + r16;
      int off = (quad & 1) * 8;
      bf8 bhv = mk8(*(const ushort4*)&KsHi[pb][key][off], *(const ushort4*)&KsHi[pb][key][off + 4]);
      bf8 blv = mk8(*(const ushort4*)&KsLo[pb][key][off], *(const ushort4*)&KsLo[pb][key][off + 4]);
      f4 z = {0.f, 0.f, 0.f, 0.f};
      z = __builtin_amdgcn_mfma_f32_16x16x32_bf16(qfrag, bhv, z, 0, 0, 0);
      z = __builtin_amdgcn_mfma_f32_16x16x32_bf16(qfrag, blv, z, 0, 0, 0);
      S[tt] = z;
    }

    float sv[4][4];
    #pragma unroll
    for (int rg = 0; rg < 4; ++rg) {
      int rowb = w * 16 + quad * 4 + rg;
      u32 mw0 = maskS[rowb][2 * (c - c0)];
      u32 mw1 = maskS[rowb][2 * (c - c0) + 1];
      #pragma unroll
      for (int tt = 0; tt < 4; ++tt) {
        u32 mword = (tt & 2) ? mw1 : mw0;
        int bit = (tt & 1) * 16 + r16;
        int bk = buckS[pb][rowb][tt * 16 + r16] & 31;
        float rel = qe_s[w][quad * 4 + rg][bk];
        float sc = S[tt][rg] + rel;
        sc += ((mword >> bit) & 1u) ? 0.f : -1.0e9f;
        sv[rg][tt] = sc;
      }
    }
    #pragma unroll
    for (int rg = 0; rg < 4; ++rg) {
      float tm = fmaxf(fmaxf(sv[rg][0], sv[rg][1]), fmaxf(sv[rg][2], sv[rg][3]));
      #pragma unroll
      for (int o = 1; o < 16; o <<= 1) tm = fmaxf(tm, __shfl_xor(tm, o));
      float nm = fmaxf(mrun[rg], tm);
      float al = __expf(mrun[rg] - nm);
      mrun[rg] = nm;
      float ps = 0.f;
      #pragma unroll
      for (int tt = 0; tt < 4; ++tt) {
        float p = __expf(sv[rg][tt] - nm);
        ps += p;
        Ps[w][quad * 4 + rg][tt * 16 + r16] = f2bf(p);
      }
      #pragma unroll
      for (int o = 1; o < 16; o <<= 1) ps += __shfl_xor(ps, o);
      lrun[rg] = lrun[rg] * al + ps;
      Oacc[rg] *= al;
    }
    #pragma unroll
    for (int half = 0; half < 2; ++half) {
      bf8 pa = *(const bf8*)&Ps[w][r16][half * 32 + quad * 8];
      bf8 vb = mk8(*(const ushort4*)&Vt[pb][r16][half * 32 + quad * 8],
                   *(const ushort4*)&Vt[pb][r16][half * 32 + quad * 8 + 4]);
      Oacc = __builtin_amdgcn_mfma_f32_16x16x32_bf16(pa, vb, Oacc, 0, 0, 0);
    }

    if (pf) store_chunk(pb ^ 1);
  }

  #pragma unroll
  for (int rg = 0; rg < 4; ++rg) {
    int gi = i0 + w * 16 + quad * 4 + rg;
    if (gi < N1) {
      size_t base = ((size_t)(bh * NSPLIT + s) * N1 + gi);
      Opart[base * 16 + r16] = Oacc[rg];
      if (r16 == 0) {
        mpart[base] = mrun[rg];
        lpart[base] = lrun[rg];
      }
    }
  }
}

// ---------------------------------------------------------------- combine split partials (exact fp32)
__global__ void attn_combine_kernel(const float* __restrict__ Opart,
                                    const float* __restrict__ mpart,
                                    const float* __restrict__ lpart,
                                    float* __restrict__ ctx) {
  int idx = blockIdx.x * 256 + threadIdx.x;
  if (idx >= BB * NH * N1) return;
  int q = idx % N1; int bh = idx / N1; int h = bh & 7; int b = bh >> 3;
  float ms[NSPLIT];
  float m = -BIGF;
  #pragma unroll
  for (int s = 0; s < NSPLIT; ++s) {
    ms[s] = mpart[(size_t)(bh * NSPLIT + s) * N1 + q];
    m = fmaxf(m, ms[s]);
  }
  float l = 0.f;
  float o[16];
  #pragma unroll
  for (int d = 0; d < DK; ++d) o[d] = 0.f;
  #pragma unroll
  for (int s = 0; s < NSPLIT; ++s) {
    float wgt = __expf(ms[s] - m);
    size_t base = (size_t)(bh * NSPLIT + s) * N1 + q;
    l += lpart[base] * wgt;
    const float* op = Opart + base * 16;
    #pragma unroll
    for (int d = 0; d < DK; ++d) o[d] += op[d] * wgt;
  }
  float inv = 1.0f / l;
  float* orow = ctx + ((size_t)b * N1 + q) * DM + h * DK;
  #pragma unroll
  for (int d = 0; d < DK; ++d) orow[d] = o[d] * inv;
}

// ---------------------------------------------------------------- instance norm (+pool, +g-update)
__global__ void inorm_kernel(float* __restrict__ X, const float* __restrict__ w,
                             const float* __restrict__ b_, float* __restrict__ pool,
                             int do_g) {
  int d = blockIdx.x; int bb = blockIdx.y; int lane = threadIdx.x;
  float g_old = X[((size_t)bb * N1 + NN) * DM + d];
  float s = 0.f;
  for (int n = lane; n < N1; n += 64) s += X[((size_t)bb * N1 + n) * DM + d];
  #pragma unroll
  for (int o = 1; o < 64; o <<= 1) s += __shfl_xor(s, o);
  float mu = s * (1.0f / N1);
  float v = 0.f;
  for (int n = lane; n < N1; n += 64) {
    float tt = X[((size_t)bb * N1 + n) * DM + d] - mu;
    v += tt * tt;
  }
  #pragma unroll
  for (int o = 1; o < 64; o <<= 1) v += __shfl_xor(v, o);
  float var = v * (1.0f / N1);
  float scv = rsqrtf(var + 1e-5f) * w[d];
  float sh = b_[d];
  for (int n = lane; n < N1; n += 64) {
    size_t id = ((size_t)bb * N1 + n) * DM + d;
    X[id] = (X[id] - mu) * scv + sh;
  }
  if (lane == 0) {
    float hmean = ((s - g_old) * (1.0f / NN) - mu) * scv + sh;
    if (pool) pool[bb * DM + d] = hmean;
    if (do_g) X[((size_t)bb * N1 + NN) * DM + d] += hmean;
  }
}

// ---------------------------------------------------------------- p_multi + (h + pm) fused
__global__ void pmadd_kernel(const float* __restrict__ X, const float* __restrict__ pools,
                             float* __restrict__ out_pm, float* __restrict__ tmp2) {
  int idx = blockIdx.x * 256 + threadIdx.x;
  if (idx >= BB * NN * DM) return;
  int d = idx % DM; int n = (idx / DM) % NN; int b = idx / (DM * NN);
  int pd = b * DM + d;
  float pmv = (pools[pd] + pools[BB * DM + pd] + pools[2 * BB * DM + pd]) * (1.0f / 3.0f);
  tmp2[idx] = X[((size_t)b * N1 + n) * DM + d] + pmv;
  if (n == 0) out_pm[pd] = pmv;
}

// ================================================================ launch
extern "C" void kernel_launch(void* const* d_in, const int* in_sizes, int n_in,
                              void* d_out, int out_size, void* d_ws, size_t ws_size,
                              hipStream_t stream) {
  const float* coords = (const float*)d_in[0];
  const float* inW    = (const float*)d_in[1];
  const float* inb    = (const float*)d_in[2];
  const float* gnode  = (const float*)d_in[3];
  const float* Wq     = (const float*)d_in[4];
  const float* Wk     = (const float*)d_in[5];
  const float* Wv     = (const float*)d_in[6];
  const float* Wo     = (const float*)d_in[7];
  const float* emb    = (const float*)d_in[8];
  const float* W1     = (const float*)d_in[9];
  const float* b1     = (const float*)d_in[10];
  const float* W2     = (const float*)d_in[11];
  const float* b2     = (const float*)d_in[12];
  const float* n1w    = (const float*)d_in[13];
  const float* n1b    = (const float*)d_in[14];
  const float* n2w    = (const float*)d_in[15];
  const float* n2b    = (const float*)d_in[16];
  const float* outW   = (const float*)d_in[17];
  const float* outb   = (const float*)d_in[18];
  float* out = (float*)d_out;

  char* wsp = (char*)d_ws;
  size_t off = 0;
  auto alloc = [&](size_t bytes) -> void* {
    off = (off + 255) & ~(size_t)255;
    void* p = wsp + off;
    off += bytes;
    return p;
  };
  const size_t XB = (size_t)BB * N1 * DM * 4;
  float* X0   = (float*)alloc(XB);
  float* X1   = (float*)alloc(XB);
  float* Qb   = (float*)alloc(XB);
  float* Kbuf = (float*)alloc(XB);
  float* Vbuf = (float*)alloc(XB);
  float* Cb   = (float*)alloc(XB);
  float* Yb   = (float*)alloc(XB);
  float* Fb   = (float*)alloc((size_t)BB * N1 * DFF * 4);   // also attn Opart (disjoint in time)
  unsigned char* buckp = (unsigned char*)alloc((size_t)BB * N1 * BSTR);
  unsigned long long* adj = (unsigned long long*)alloc((size_t)BB * N1 * ADJW * 8);
  u32* connb = (u32*)alloc((size_t)BB * N1 * MW * 4);
  float* sqb   = (float*)alloc((size_t)BB * NN * 4);
  float* pools = (float*)alloc((size_t)NLAYERS * BB * DM * 4);
  float* tmp   = (float*)alloc((size_t)BB * NN * DM * 4);   // also attn m/l partials
  u16* PH = (u16*)alloc((size_t)PW_TOT * 2);
  u16* PL = (u16*)alloc((size_t)PW_TOT * 2);
  float* d2 = (float*)alloc((size_t)BB * NN * NN * 4);      // 8 MB gram keys

  float* Opart = Fb;
  float* mpart = tmp;
  float* lpart = tmp + 65600;

  prepack_kernel<<<296, 256, 0, stream>>>(Wq, Wk, Wv, Wo, W1, W2, outW, PH, PL);
  embed_kernel<<<(BB * N1 * DM + 255) / 256, 256, 0, stream>>>(coords, inW, inb, gnode, X0);
  bucket_kernel<<<(BB * N1 * BSTR + 255) / 256, 256, 0, stream>>>(coords, buckp);
  g_update_kernel<<<dim3(DM, BB), 64, 0, stream>>>(X0);   // layer 0 g-update

  float* Xin = X0; float* Xout = X1;
  const int M = BB * N1;
  const int GX = 33;     // ceil(129 m-tiles / 4 waves)
  for (int l = 0; l < NLAYERS; ++l) {
    hipMemsetAsync(adj, 0, (size_t)BB * N1 * ADJW * 8, stream);
    rowsq_kernel<<<(BB * NN + 63) / 64, 64, 0, stream>>>(Xin, sqb);
    gram_kernel<<<dim3(32, 16, BB), 256, 0, stream>>>(Xin, sqb, d2);
    knnsel_kernel<<<BB * NN / 4, 256, 0, stream>>>(d2, adj);
    connb_kernel<<<(BB * N1 + 255) / 256, 256, 0, stream>>>(adj, connb);

    gemm_qkv_kernel<<<dim3(GX, 8, 3), 256, 0, stream>>>(
        Xin,
        PH + PWQ_OFF + (size_t)l * DM * DM, PL + PWQ_OFF + (size_t)l * DM * DM,
        PH + PWK_OFF + (size_t)l * DM * DM, PL + PWK_OFF + (size_t)l * DM * DM,
        PH + PWV_OFF + (size_t)l * DM * DM, PL + PWV_OFF + (size_t)l * DM * DM,
        Qb, Kbuf, Vbuf, M);

    attn_kernel<<<dim3(33, NH * BB, NSPLIT), 128, 0, stream>>>(
        Qb, Kbuf, Vbuf, emb + (size_t)l * NBUK * DM, buckp, connb, Opart, mpart, lpart);
    attn_combine_kernel<<<(BB * NH * N1 + 255) / 256, 256, 0, stream>>>(
        Opart, mpart, lpart, Cb);

    gemm_kernel<<<dim3(GX, 8), 256, 0, stream>>>(
        Cb, PH + PWO_OFF + (size_t)l * DM * DM, PL + PWO_OFF + (size_t)l * DM * DM,
        nullptr, Xin, Yb, M, DM, DM, 0);
    inorm_kernel<<<dim3(DM, BB), 64, 0, stream>>>(Yb, n1w + l * DM, n1b + l * DM, nullptr, 0);

    gemm_kernel<<<dim3(GX, 32), 256, 0, stream>>>(
        Yb, PH + PW1_OFF + (size_t)l * DFF * DM, PL + PW1_OFF + (size_t)l * DFF * DM,
        b1 + l * DFF, nullptr, Fb, M, DM, DFF, 1);
    gemm_kernel<<<dim3(GX, 8), 256, 0, stream>>>(
        Fb, PH + PW2_OFF + (size_t)l * DM * DFF, PL + PW2_OFF + (size_t)l * DM * DFF,
        b2 + l * DM, Yb, Xout, M, DFF, DM, 0);
    inorm_kernel<<<dim3(DM, BB), 64, 0, stream>>>(Xout, n2w + l * DM, n2b + l * DM,
                                                  pools + (size_t)l * BB * DM, 1);

    float* t2 = Xin; Xin = Xout; Xout = t2;
  }

  pmadd_kernel<<<(BB * NN * DM + 255) / 256, 256, 0, stream>>>(
      Xin, pools, out + (size_t)BB * NN * DM, tmp);
  gemm_kernel<<<dim3(32, 8), 256, 0, stream>>>(
      tmp, PH + PWOUT_OFF, PL + PWOUT_OFF, outb, nullptr, out, BB * NN, DM, DM, 0);
}

// Round 9
// 570.841 us; speedup vs baseline: 1.2588x; 1.0335x over previous
//
#include <hip/hip_runtime.h>

#define BB 2
#define NN 1024
#define N1 1025
#define DM 128
#define NH 8
#define DK 16
#define DFF 512
#define NBUK 32
#define NLAYERS 3
#define KNN_K 10
#define ADJW 17          // 1025 bits -> 17 u64 words per row
#define MW 34            // 34 u32 mask words per row (1088 bits)
#define BSTR 1088        // padded bucket row stride (bytes)
#define NSPLIT 8
#define BIGF 3.0e38f

// prepacked-weight element offsets (see prepack_kernel)
#define PWQ_OFF 0
#define PWK_OFF 49152
#define PWV_OFF 98304
#define PWO_OFF 147456
#define PW1_OFF 196608
#define PW2_OFF 393216
#define PWOUT_OFF 589824
#define PW_TOT 606208

typedef __attribute__((ext_vector_type(8))) short bf8;
typedef __attribute__((ext_vector_type(4))) float f4;
typedef unsigned short u16;
typedef unsigned int u32;

__device__ __forceinline__ u16 f2bf(float x) {
  unsigned u = __float_as_uint(x);
  return (u16)((u + 0x7fff + ((u >> 16) & 1)) >> 16);   // RNE
}
__device__ __forceinline__ float bf2f(u16 u) {
  return __uint_as_float(((unsigned)u) << 16);
}
__device__ __forceinline__ bf8 mk8(ushort4 a, ushort4 b) {
  bf8 r;
  r[0] = (short)a.x; r[1] = (short)a.y; r[2] = (short)a.z; r[3] = (short)a.w;
  r[4] = (short)b.x; r[5] = (short)b.y; r[6] = (short)b.z; r[7] = (short)b.w;
  return r;
}

// ---------------------------------------------------------------- weight prepack
// B-fragment layout: elem((nt,ks,lane,j)) = W[nt*16 + (lane&15)][ks*32 + (lane>>4)*8 + j]
__global__ void prepack_kernel(const float* __restrict__ Wq, const float* __restrict__ Wk,
                               const float* __restrict__ Wv, const float* __restrict__ Wo,
                               const float* __restrict__ W1, const float* __restrict__ W2,
                               const float* __restrict__ oW,
                               u16* __restrict__ PH, u16* __restrict__ PL) {
  int idx = blockIdx.x * 256 + threadIdx.x;   // lane-group id (8 elems each)
  if (idx >= 75776) return;
  const float* W; int rel, Kdim;
  if (idx < 24576) {
    int seg = idx / 6144; rel = idx % 6144; Kdim = 128;
    W = seg == 0 ? Wq : seg == 1 ? Wk : seg == 2 ? Wv : Wo;
  } else if (idx < 49152) { rel = idx - 24576; Kdim = 128; W = W1; }
  else if (idx < 73728)   { rel = idx - 49152; Kdim = 512; W = W2; }
  else                    { rel = idx - 73728; Kdim = 128; W = oW; }
  int lane = rel & 63;
  int g = rel >> 6;
  int ksteps = Kdim >> 5;
  int ks = g % ksteps, nt = g / ksteps;
  int n = nt * 16 + (lane & 15);
  int k = ks * 32 + (lane >> 4) * 8;
  const float* p = W + (size_t)n * Kdim + k;
  u16* ph = PH + (size_t)idx * 8;
  u16* pl = PL + (size_t)idx * 8;
  #pragma unroll
  for (int q = 0; q < 8; ++q) {
    float x = p[q];
    u16 hh = f2bf(x);
    ph[q] = hh;
    pl[q] = f2bf(x - bf2f(hh));
  }
}

// ---------------------------------------------------------------- embed
__global__ void embed_kernel(const float* __restrict__ coords, const float* __restrict__ inW,
                             const float* __restrict__ inb, const float* __restrict__ gnode,
                             float* __restrict__ X) {
  int idx = blockIdx.x * 256 + threadIdx.x;
  if (idx >= BB * N1 * DM) return;
  int d = idx % DM; int r = idx / DM; int n = r % N1; int b = r / N1;
  float v;
  if (n < NN) {
    float cx = coords[(b * NN + n) * 2 + 0], cy = coords[(b * NN + n) * 2 + 1];
    v = cx * inW[d * 2 + 0] + cy * inW[d * 2 + 1] + inb[d];
  } else {
    v = gnode[d];
  }
  X[idx] = v;
}

// ---------------------------------------------------------------- bucket (padded rows)
__global__ void bucket_kernel(const float* __restrict__ coords, unsigned char* __restrict__ buckp) {
  int idx = blockIdx.x * 256 + threadIdx.x;
  if (idx >= BB * N1 * BSTR) return;
  int j = idx % BSTR; int r = idx / BSTR; int i = r % N1; int b = r / N1;
  unsigned char v = 0;
  if (j < N1) {
    float xi = 0.f, yi = 0.f, xj = 0.f, yj = 0.f;
    if (i < NN) { xi = coords[(b * NN + i) * 2]; yi = coords[(b * NN + i) * 2 + 1]; }
    if (j < NN) { xj = coords[(b * NN + j) * 2]; yj = coords[(b * NN + j) * 2 + 1]; }
    float dx = xi - xj, dy = yi - yj;
    float dist = sqrtf(dx * dx + dy * dy);
    int bu = (int)(dist * 32.0f);
    bu = bu < 0 ? 0 : (bu > 31 ? 31 : bu);
    v = (unsigned char)bu;
  }
  buckp[idx] = v;
}

// ---------------------------------------------------------------- g += mean(h) (layer 0 only)
__global__ void g_update_kernel(float* __restrict__ X) {
  int d = blockIdx.x; int b = blockIdx.y; int lane = threadIdx.x;  // 64 threads
  float s = 0.f;
  for (int n = lane; n < NN; n += 64) s += X[((size_t)b * N1 + n) * DM + d];
  for (int o = 32; o; o >>= 1) s += __shfl_down(s, o);
  if (lane == 0) X[((size_t)b * N1 + NN) * DM + d] += s * (1.0f / NN);
}

// ---------------------------------------------------------------- X split (3-level exact) + rowsq + adj zero
__global__ __launch_bounds__(256) void xsplit_kernel(
    const float* __restrict__ X, u16* __restrict__ XH, u16* __restrict__ XM,
    u16* __restrict__ XL, float* __restrict__ sqb, unsigned long long* __restrict__ adj) {
  int t = threadIdx.x;
  int tid = blockIdx.x * 256 + t;
  if (tid < BB * N1 * ADJW) adj[tid] = 0ull;      // 513*256 = 131328 >= 34850
  int wave = blockIdx.x * 4 + (t >> 6), lane = t & 63;
  if (wave >= BB * N1) return;
  float2 v = *(const float2*)(X + (size_t)wave * DM + lane * 2);
  u16 h0 = f2bf(v.x); float r1 = v.x - bf2f(h0);
  u16 m0 = f2bf(r1);  u16 l0 = f2bf(r1 - bf2f(m0));
  u16 h1 = f2bf(v.y); float r2 = v.y - bf2f(h1);
  u16 m1 = f2bf(r2);  u16 l1 = f2bf(r2 - bf2f(m1));
  size_t o = (size_t)wave * DM + lane * 2;
  *(u32*)&XH[o] = (u32)h0 | ((u32)h1 << 16);
  *(u32*)&XM[o] = (u32)m0 | ((u32)m1 << 16);
  *(u32*)&XL[o] = (u32)l0 | ((u32)l1 << 16);
  float sq = v.x * v.x + v.y * v.y;
  #pragma unroll
  for (int oo = 1; oo < 64; oo <<= 1) sq += __shfl_xor(sq, oo);
  if (lane == 0) {
    int b = wave / N1, n = wave % N1;
    if (n < NN) sqb[b * NN + n] = sq;
  }
}

// ---------------------------------------------------------------- exact MFMA gram (3-level, prestaged)
__global__ __launch_bounds__(256) void gram_kernel(
    const u16* __restrict__ XH, const u16* __restrict__ XM, const u16* __restrict__ XL,
    const float* __restrict__ sqb, float* __restrict__ d2) {
  __shared__ __align__(16) u16 AsH[32][72];
  __shared__ __align__(16) u16 AsM[32][72];
  __shared__ __align__(16) u16 AsL[32][72];
  __shared__ __align__(16) u16 BsH[64][72];
  __shared__ __align__(16) u16 BsM[64][72];
  __shared__ __align__(16) u16 BsL[64][72];
  int b = blockIdx.z;
  int m0 = blockIdx.x * 32, n0 = blockIdx.y * 64;
  size_t boff = (size_t)b * N1;
  int t = threadIdx.x;
  int lane = t & 63, w = t >> 6;
  int wm = (w >> 1) * 16, wn = (w & 1) * 32;
  int quad = lane >> 4, r16 = lane & 15;

  f4 acc0 = {0.f, 0.f, 0.f, 0.f}, acc1 = {0.f, 0.f, 0.f, 0.f};
  int ar = t >> 3, as_ = (t & 7) * 8;     // A: 32 rows x 8 segs of 8
  int br = t >> 2, bs_ = (t & 3) * 16;    // B: 64 rows x 4 segs of 16

  for (int k0 = 0; k0 < DM; k0 += 64) {
    {
      size_t src = (boff + m0 + ar) * DM + k0 + as_;
      *(bf8*)&AsH[ar][as_] = *(const bf8*)(XH + src);
      *(bf8*)&AsM[ar][as_] = *(const bf8*)(XM + src);
      *(bf8*)&AsL[ar][as_] = *(const bf8*)(XL + src);
    }
    {
      size_t src = (boff + n0 + br) * DM + k0 + bs_;
      *(bf8*)&BsH[br][bs_] = *(const bf8*)(XH + src);
      *(bf8*)&BsH[br][bs_ + 8] = *(const bf8*)(XH + src + 8);
      *(bf8*)&BsM[br][bs_] = *(const bf8*)(XM + src);
      *(bf8*)&BsM[br][bs_ + 8] = *(const bf8*)(XM + src + 8);
      *(bf8*)&BsL[br][bs_] = *(const bf8*)(XL + src);
      *(bf8*)&BsL[br][bs_ + 8] = *(const bf8*)(XL + src + 8);
    }
    __syncthreads();
    #pragma unroll
    for (int ks = 0; ks < 64; ks += 16) {
      int seg = (quad & 1) * 8;
      bf8 aHM = *(const bf8*)((quad < 2) ? &AsH[wm + r16][ks + seg] : &AsM[wm + r16][ks + seg]);
      bf8 aHL = *(const bf8*)((quad < 2) ? &AsH[wm + r16][ks + seg] : &AsL[wm + r16][ks + seg]);
      #pragma unroll
      for (int tt = 0; tt < 2; ++tt) {
        int nr = wn + tt * 16 + r16;
        bf8 bH = *(const bf8*)&BsH[nr][ks + seg];
        bf8 bM = *(const bf8*)&BsM[nr][ks + seg];
        bf8 b3 = *(const bf8*)((quad < 2) ? &BsL[nr][ks + seg] : &BsH[nr][ks + seg]);
        f4& a = tt ? acc1 : acc0;
        a = __builtin_amdgcn_mfma_f32_16x16x32_bf16(aHM, bH, a, 0, 0, 0);  // HH' + MH'
        a = __builtin_amdgcn_mfma_f32_16x16x32_bf16(aHM, bM, a, 0, 0, 0);  // HM' + MM'
        a = __builtin_amdgcn_mfma_f32_16x16x32_bf16(aHL, b3, a, 0, 0, 0);  // HL' + LH'
      }
    }
    __syncthreads();
  }

  #pragma unroll
  for (int tt = 0; tt < 2; ++tt) {
    f4 a = tt ? acc1 : acc0;
    int n = n0 + wn + tt * 16 + r16;
    float sj = sqb[b * NN + n];
    #pragma unroll
    for (int reg = 0; reg < 4; ++reg) {
      int m = m0 + wm + quad * 4 + reg;
      float si = sqb[b * NN + m];
      float v = (m == n) ? BIGF : (si + sj - 2.f * a[reg]);
      d2[((size_t)b * NN + m) * NN + n] = v;
    }
  }
}

// ---------------------------------------------------------------- top-10 select -> adjacency bits
__global__ __launch_bounds__(256) void knnsel_kernel(const float* __restrict__ d2,
                                                     unsigned long long* __restrict__ adj) {
  __shared__ float dd[4][NN];
  int blk = blockIdx.x;
  int b = blk / (NN / 4);
  int i0 = (blk % (NN / 4)) * 4;
  int t = threadIdx.x, lane = t & 63, w = t >> 6;

  const float4* src = (const float4*)(d2 + ((size_t)b * NN + i0) * NN);
  float4* dst = (float4*)&dd[0][0];
  #pragma unroll
  for (int x = 0; x < 4; ++x) dst[t + x * 256] = src[t + x * 256];
  __syncthreads();

  int i = i0 + w;
  for (int it = 0; it < KNN_K; ++it) {
    float bv = BIGF; int bi = 0x3fffffff;
    for (int j = lane; j < NN; j += 64) {
      float v = dd[w][j];
      if (v < bv) { bv = v; bi = j; }
    }
    #pragma unroll
    for (int o = 1; o < 64; o <<= 1) {
      float ov = __shfl_xor(bv, o); int oi = __shfl_xor(bi, o);
      if (ov < bv || (ov == bv && oi < bi)) { bv = ov; bi = oi; }
    }
    if (lane == 0) {
      dd[w][bi] = BIGF;
      atomicOr(&adj[((size_t)b * N1 + i) * ADJW + (bi >> 6)], 1ull << (bi & 63));
      atomicOr(&adj[((size_t)b * N1 + bi) * ADJW + (i >> 6)], 1ull << (i & 63));
    }
  }
}

// ---------------------------------------------------------------- conn bitmask build
__global__ void connb_kernel(const unsigned long long* __restrict__ adj,
                             u32* __restrict__ connb) {
  int idx = blockIdx.x * 256 + threadIdx.x;
  if (idx >= BB * N1) return;
  int b = idx / N1, i = idx % N1;
  const u32* arow = (const u32*)(adj + (size_t)(b * N1 + i) * ADJW);
  u32* crow = connb + (size_t)(b * N1 + i) * MW;
  bool allv = (i == 0 || i == NN);
  int lo = 0, hi = -1;
  if (i < NN) {
    int bs = i & ~127;
    lo = i - 11 < bs ? bs : i - 11;
    int be = bs + 127;
    hi = i + 11 > be ? be : i + 11;
  }
  for (int w = 0; w < MW; ++w) {
    u32 v;
    if (allv) {
      v = 0xffffffffu;
    } else {
      v = arow[w];
      int a = lo - 32 * w, bnd = hi - 32 * w;
      if (a < 0) a = 0; if (bnd > 31) bnd = 31;
      if (a <= bnd) v |= (0xffffffffu << a) & (0xffffffffu >> (31 - bnd));
      if (w == 0) v |= 1u;
      if (w == 32) v |= 1u;
      int dg = i - 32 * w;
      if (dg >= 0 && dg < 32) v |= 1u << dg;
    }
    if (w == 32) v &= 1u;
    else if (w == 33) v = 0u;
    crow[w] = v;
  }
}

// ---------------------------------------------------------------- direct-fragment GEMM (16x16/wave)
// Pure load+MFMA: A from prestaged hi/lo bf16, B from prepacked fragments. No LDS/barriers.
__device__ __forceinline__ void gemm_dev16(
    const u16* __restrict__ AH, const u16* __restrict__ AL,
    const u16* __restrict__ PH, const u16* __restrict__ PL,
    const float* __restrict__ bias, const float* __restrict__ res,
    float* __restrict__ outF, u16* __restrict__ outH, u16* __restrict__ outL,
    int M, int Kdim, int Nout, int relu, int mt, int nt) {
  int lane = threadIdx.x & 63;
  int quad = lane >> 4, r16 = lane & 15;
  int ksteps = Kdim >> 5;
  f4 acc = {0.f, 0.f, 0.f, 0.f};

  int m0 = mt * 16;
  int mrow = m0 + r16; if (mrow >= M) mrow = M - 1;   // clamp; result discarded
  const u16* aph = AH + (size_t)mrow * Kdim + quad * 8;
  const u16* apl = AL + (size_t)mrow * Kdim + quad * 8;
  const u16* ph = PH + ((size_t)nt * ksteps * 64 + lane) * 8;
  const u16* pl = PL + ((size_t)nt * ksteps * 64 + lane) * 8;

  #pragma unroll 4
  for (int ks = 0; ks < ksteps; ++ks) {
    bf8 aH = *(const bf8*)(aph);
    bf8 aL = *(const bf8*)(apl);
    aph += 32; apl += 32;
    bf8 bH = *(const bf8*)(ph + (size_t)ks * 512);
    bf8 bL = *(const bf8*)(pl + (size_t)ks * 512);
    acc = __builtin_amdgcn_mfma_f32_16x16x32_bf16(aH, bH, acc, 0, 0, 0);
    acc = __builtin_amdgcn_mfma_f32_16x16x32_bf16(aH, bL, acc, 0, 0, 0);
    acc = __builtin_amdgcn_mfma_f32_16x16x32_bf16(aL, bH, acc, 0, 0, 0);
  }

  if (m0 >= M) return;
  int n = nt * 16 + r16;
  #pragma unroll
  for (int reg = 0; reg < 4; ++reg) {
    int m = m0 + quad * 4 + reg;    // C layout: col=lane&15, row=quad*4+reg
    if (m < M) {
      float v = acc[reg];
      if (bias) v += bias[n];
      if (relu) v = fmaxf(v, 0.f);
      if (res) v += res[(size_t)m * Nout + n];
      size_t oi = (size_t)m * Nout + n;
      if (outF) outF[oi] = v;
      if (outH) {
        u16 hh = f2bf(v);
        outH[oi] = hh;
        outL[oi] = f2bf(v - bf2f(hh));
      }
    }
  }
}

__global__ __launch_bounds__(256) void gemm_kernel(
    const u16* __restrict__ AH, const u16* __restrict__ AL,
    const u16* __restrict__ PH, const u16* __restrict__ PL,
    const float* __restrict__ bias, const float* __restrict__ res,
    float* __restrict__ outF, u16* __restrict__ outH, u16* __restrict__ outL,
    int M, int Kdim, int Nout, int relu) {
  gemm_dev16(AH, AL, PH, PL, bias, res, outF, outH, outL, M, Kdim, Nout, relu,
             blockIdx.x * 4 + (threadIdx.x >> 6), blockIdx.y);
}

// QKV: z=0 Q (fp32 + 0.25-scaled split), z=1 K (split), z=2 V (bf16)
__global__ __launch_bounds__(256) void gemm_qkv_kernel(
    const u16* __restrict__ AH, const u16* __restrict__ AL,
    const u16* __restrict__ QWH, const u16* __restrict__ QWL,
    const u16* __restrict__ KWH, const u16* __restrict__ KWL,
    const u16* __restrict__ VWH, const u16* __restrict__ VWL,
    float* __restrict__ Qo, u16* __restrict__ QH, u16* __restrict__ QL,
    u16* __restrict__ KH, u16* __restrict__ KL, u16* __restrict__ Vbf, int M) {
  int z = blockIdx.z;
  const u16* PH = z == 0 ? QWH : (z == 1 ? KWH : VWH);
  const u16* PL = z == 0 ? QWL : (z == 1 ? KWL : VWL);
  int lane = threadIdx.x & 63;
  int quad = lane >> 4, r16 = lane & 15;
  int mt = blockIdx.x * 4 + (threadIdx.x >> 6), nt = blockIdx.y;
  f4 acc = {0.f, 0.f, 0.f, 0.f};
  int m0 = mt * 16;
  int mrow = m0 + r16; if (mrow >= M) mrow = M - 1;
  const u16* aph = AH + (size_t)mrow * DM + quad * 8;
  const u16* apl = AL + (size_t)mrow * DM + quad * 8;
  const u16* ph = PH + ((size_t)nt * 4 * 64 + lane) * 8;
  const u16* pl = PL + ((size_t)nt * 4 * 64 + lane) * 8;
  #pragma unroll
  for (int ks = 0; ks < 4; ++ks) {
    bf8 aH = *(const bf8*)(aph);
    bf8 aL = *(const bf8*)(apl);
    aph += 32; apl += 32;
    bf8 bH = *(const bf8*)(ph + (size_t)ks * 512);
    bf8 bL = *(const bf8*)(pl + (size_t)ks * 512);
    acc = __builtin_amdgcn_mfma_f32_16x16x32_bf16(aH, bH, acc, 0, 0, 0);
    acc = __builtin_amdgcn_mfma_f32_16x16x32_bf16(aH, bL, acc, 0, 0, 0);
    acc = __builtin_amdgcn_mfma_f32_16x16x32_bf16(aL, bH, acc, 0, 0, 0);
  }
  if (m0 >= M) return;
  int n = nt * 16 + r16;
  #pragma unroll
  for (int reg = 0; reg < 4; ++reg) {
    int m = m0 + quad * 4 + reg;
    if (m >= M) continue;
    float v = acc[reg];
    size_t oi = (size_t)m * DM + n;
    if (z == 0) {
      Qo[oi] = v;
      float sv = v * 0.25f;
      u16 hh = f2bf(sv);
      QH[oi] = hh;
      QL[oi] = f2bf(sv - bf2f(hh));
    } else if (z == 1) {
      u16 hh = f2bf(v);
      KH[oi] = hh;
      KL[oi] = f2bf(v - bf2f(hh));
    } else {
      Vbf[oi] = f2bf(v);
    }
  }
}

// ---------------------------------------------------------------- qe = Q . emb^T (per head/bucket)
__global__ __launch_bounds__(256) void qe_kernel(const float* __restrict__ Qb,
                                                 const float* __restrict__ emb_l,
                                                 float* __restrict__ qe_all) {
  __shared__ float qs[4][DM];
  int t = threadIdx.x, w = t >> 6, lane = t & 63;
  int r = blockIdx.x * 4 + w;
  bool valid = r < BB * N1;
  if (valid) {
    float2 v = *(const float2*)(Qb + (size_t)r * DM + lane * 2);
    qs[w][lane * 2] = v.x;
    qs[w][lane * 2 + 1] = v.y;
  }
  __syncthreads();
  if (!valid) return;
  int b = r / N1, n = r % N1;
  #pragma unroll
  for (int j = 0; j < 4; ++j) {
    int o = lane + 64 * j;
    int h = o >> 5, bk = o & 31;
    const float* er = emb_l + (size_t)bk * DM + h * DK;
    const float* q = &qs[w][h * DK];
    float s = 0.f;
    #pragma unroll
    for (int d = 0; d < DK; ++d) s += q[d] * er[d];
    qe_all[(((size_t)b * NH + h) * N1 + n) * 32 + bk] = s;
  }
}

// ---------------------------------------------------------------- MFMA flash attention, key-split
// All operands pre-split bf16; staging is pure memory movement.
#define CH 64
#define NCH 17
__global__ __launch_bounds__(128) void attn_kernel(
    const u16* __restrict__ QH, const u16* __restrict__ QL,
    const u16* __restrict__ KH, const u16* __restrict__ KL,
    const u16* __restrict__ Vbf, const float* __restrict__ qe_all,
    const unsigned char* __restrict__ buckp, const u32* __restrict__ connb,
    float* __restrict__ Opart, float* __restrict__ mpart, float* __restrict__ lpart) {
  __shared__ __align__(16) u16 KsHi[2][CH][20];
  __shared__ __align__(16) u16 KsLo[2][CH][20];
  __shared__ __align__(16) u16 Vt[2][DK][68];
  __shared__ __align__(16) u16 Ps[2][16][72];
  __shared__ __align__(16) float qe_s[2][16][36];
  __shared__ u32 maskS[32][6];
  __shared__ unsigned char buckS[2][32][68];

  int qt = blockIdx.x;
  int h = blockIdx.y & 7, b = blockIdx.y >> 3;
  int s = blockIdx.z;
  int c0 = (NCH * s) / NSPLIT, c1 = (NCH * (s + 1)) / NSPLIT;
  int nwm = 2 * (c1 - c0);
  int t = threadIdx.x, lane = t & 63, w = t >> 6;
  int quad = lane >> 4, r16 = lane & 15;
  int i0 = qt * 32;
  int iw = i0 + w * 16;
  int bh = b * NH + h;

  for (int x = t; x < 32 * nwm; x += 128) {
    int rr = x / nwm, ww = x % nwm;
    int gi = i0 + rr; if (gi > NN) gi = NN;
    maskS[rr][ww] = connb[((size_t)b * N1 + gi) * MW + 2 * c0 + ww];
  }
  // qe table: per-row clamped load (valid rows get exact values)
  #pragma unroll
  for (int e = 0; e < 2; ++e) {
    int x = lane + e * 64;
    int rr = x >> 3, bk = (x & 7) * 4;
    int gi = iw + rr; if (gi > NN) gi = NN;
    f4 v = *(const f4*)(qe_all + (((size_t)b * NH + h) * N1 + gi) * 32 + bk);
    *(f4*)&qe_s[w][rr][bk] = v;
  }
  bf8 qfrag;
  {
    int gi = iw + r16; if (gi > NN) gi = NN;
    const u16* qsrc = (quad < 2 ? QH : QL) + ((size_t)(b * N1 + gi) * DM + h * DK + (quad & 1) * 8);
    qfrag = *(const bf8*)qsrc;
  }

  ushort4 khr[2], klr[2], vvr[2]; u32 bkr[4];
  auto load_chunk = [&](int c) {
    int j0 = c * CH;
    #pragma unroll
    for (int ii = 0; ii < 2; ++ii) {
      int x = t + ii * 128;
      int key = x >> 2, ds = (x & 3) * 4;
      int jg = j0 + key; if (jg > NN) jg = NN;
      size_t src = (size_t)(b * N1 + jg) * DM + h * DK + ds;
      khr[ii] = *(const ushort4*)(KH + src);
      klr[ii] = *(const ushort4*)(KL + src);
      vvr[ii] = *(const ushort4*)(Vbf + src);
    }
    #pragma unroll
    for (int ii = 0; ii < 4; ++ii) {
      int x = t + ii * 128;
      int rr = x >> 4, c4 = (x & 15) * 4;
      int gi = i0 + rr; if (gi > NN) gi = NN;
      bkr[ii] = *(const u32*)(buckp + ((size_t)b * N1 + gi) * BSTR + j0 + c4);
    }
  };
  auto store_chunk = [&](int pb) {
    #pragma unroll
    for (int ii = 0; ii < 2; ++ii) {
      int x = t + ii * 128;
      int key = x >> 2, ds = (x & 3) * 4;
      *(ushort4*)&KsHi[pb][key][ds] = khr[ii];
      *(ushort4*)&KsLo[pb][key][ds] = klr[ii];
      Vt[pb][ds + 0][key] = vvr[ii].x;
      Vt[pb][ds + 1][key] = vvr[ii].y;
      Vt[pb][ds + 2][key] = vvr[ii].z;
      Vt[pb][ds + 3][key] = vvr[ii].w;
    }
    #pragma unroll
    for (int ii = 0; ii < 4; ++ii) {
      int x = t + ii * 128;
      int rr = x >> 4, c4 = (x & 15) * 4;
      *(u32*)&buckS[pb][rr][c4] = bkr[ii];
    }
  };

  f4 Oacc = {0.f, 0.f, 0.f, 0.f};
  float mrun[4] = {-1e30f, -1e30f, -1e30f, -1e30f};
  float lrun[4] = {0.f, 0.f, 0.f, 0.f};

  load_chunk(c0);
  store_chunk(0);

  for (int c = c0; c < c1; ++c) {
    int pb = (c - c0) & 1;
    bool pf = (c + 1 < c1);
    if (pf) load_chunk(c + 1);
    __syncthreads();

    f4 S[4];
    #pragma unroll
    for (int tt = 0; tt < 4; ++tt) {
      int key = tt * 16 + r16;
      int off = (quad & 1) * 8;
      bf8 bhv = mk8(*(const ushort4*)&KsHi[pb][key][off], *(const ushort4*)&KsHi[pb][key][off + 4]);
      bf8 blv = mk8(*(const ushort4*)&KsLo[pb][key][off], *(const ushort4*)&KsLo[pb][key][off + 4]);
      f4 z = {0.f, 0.f, 0.f, 0.f};
      z = __builtin_amdgcn_mfma_f32_16x16x32_bf16(qfrag, bhv, z, 0, 0, 0);
      z = __builtin_amdgcn_mfma_f32_16x16x32_bf16(qfrag, blv, z, 0, 0, 0);
      S[tt] = z;
    }

    float sv[4][4];
    #pragma unroll
    for (int rg = 0; rg < 4; ++rg) {
      int rowb = w * 16 + quad * 4 + rg;
      u32 mw0 = maskS[rowb][2 * (c - c0)];
      u32 mw1 = maskS[rowb][2 * (c - c0) + 1];
      #pragma unroll
      for (int tt = 0; tt < 4; ++tt) {
        u32 mword = (tt & 2) ? mw1 : mw0;
        int bit = (tt & 1) * 16 + r16;
        int bk = buckS[pb][rowb][tt * 16 + r16] & 31;
        float rel = qe_s[w][quad * 4 + rg][bk];
        float sc = S[tt][rg] + rel;
        sc += ((mword >> bit) & 1u) ? 0.f : -1.0e9f;
        sv[rg][tt] = sc;
      }
    }
    #pragma unroll
    for (int rg = 0; rg < 4; ++rg) {
      float tm = fmaxf(fmaxf(sv[rg][0], sv[rg][1]), fmaxf(sv[rg][2], sv[rg][3]));
      #pragma unroll
      for (int o = 1; o < 16; o <<= 1) tm = fmaxf(tm, __shfl_xor(tm, o));
      float nm = fmaxf(mrun[rg], tm);
      float al = __expf(mrun[rg] - nm);
      mrun[rg] = nm;
      float ps = 0.f;
      #pragma unroll
      for (int tt = 0; tt < 4; ++tt) {
        float p = __expf(sv[rg][tt] - nm);
        ps += p;
        Ps[w][quad * 4 + rg][tt * 16 + r16] = f2bf(p);
      }
      #pragma unroll
      for (int o = 1; o < 16; o <<= 1) ps += __shfl_xor(ps, o);
      lrun[rg] = lrun[rg] * al + ps;
      Oacc[rg] *= al;
    }
    #pragma unroll
    for (int half = 0; half < 2; ++half) {
      bf8 pa = *(const bf8*)&Ps[w][r16][half * 32 + quad * 8];
      bf8 vb = mk8(*(const ushort4*)&Vt[pb][r16][half * 32 + quad * 8],
                   *(const ushort4*)&Vt[pb][r16][half * 32 + quad * 8 + 4]);
      Oacc = __builtin_amdgcn_mfma_f32_16x16x32_bf16(pa, vb, Oacc, 0, 0, 0);
    }

    if (pf) store_chunk(pb ^ 1);
  }

  #pragma unroll
  for (int rg = 0; rg < 4; ++rg) {
    int gi = i0 + w * 16 + quad * 4 + rg;
    if (gi < N1) {
      size_t base = ((size_t)(bh * NSPLIT + s) * N1 + gi);
      Opart[base * 16 + r16] = Oacc[rg];
      if (r16 == 0) {
        mpart[base] = mrun[rg];
        lpart[base] = lrun[rg];
      }
    }
  }
}

// ---------------------------------------------------------------- combine split partials -> Cb hi/lo
__global__ void attn_combine_kernel(const float* __restrict__ Opart,
                                    const float* __restrict__ mpart,
                                    const float* __restrict__ lpart,
                                    u16* __restrict__ CbH, u16* __restrict__ CbL) {
  int idx = blockIdx.x * 256 + threadIdx.x;
  if (idx >= BB * NH * N1) return;
  int q = idx % N1; int bh = idx / N1; int h = bh & 7; int b = bh >> 3;
  float ms[NSPLIT];
  float m = -BIGF;
  #pragma unroll
  for (int s = 0; s < NSPLIT; ++s) {
    ms[s] = mpart[(size_t)(bh * NSPLIT + s) * N1 + q];
    m = fmaxf(m, ms[s]);
  }
  float l = 0.f;
  float o[16];
  #pragma unroll
  for (int d = 0; d < DK; ++d) o[d] = 0.f;
  #pragma unroll
  for (int s = 0; s < NSPLIT; ++s) {
    float wgt = __expf(ms[s] - m);
    size_t base = (size_t)(bh * NSPLIT + s) * N1 + q;
    l += lpart[base] * wgt;
    const float* op = Opart + base * 16;
    #pragma unroll
    for (int d = 0; d < DK; ++d) o[d] += op[d] * wgt;
  }
  float inv = 1.0f / l;
  size_t obase = ((size_t)b * N1 + q) * DM + h * DK;
  #pragma unroll
  for (int d = 0; d < DK; ++d) {
    float v = o[d] * inv;
    u16 hh = f2bf(v);
    CbH[obase + d] = hh;
    CbL[obase + d] = f2bf(v - bf2f(hh));
  }
}

// ---------------------------------------------------------------- instance norm (+pool/g, +split emit)
__global__ void inorm_kernel(float* __restrict__ X, const float* __restrict__ w,
                             const float* __restrict__ b_, float* __restrict__ pool,
                             int do_g, u16* __restrict__ oH, u16* __restrict__ oL) {
  int d = blockIdx.x; int bb = blockIdx.y; int lane = threadIdx.x;
  float g_old = X[((size_t)bb * N1 + NN) * DM + d];
  float s = 0.f;
  for (int n = lane; n < N1; n += 64) s += X[((size_t)bb * N1 + n) * DM + d];
  #pragma unroll
  for (int o = 1; o < 64; o <<= 1) s += __shfl_xor(s, o);
  float mu = s * (1.0f / N1);
  float v = 0.f;
  for (int n = lane; n < N1; n += 64) {
    float tt = X[((size_t)bb * N1 + n) * DM + d] - mu;
    v += tt * tt;
  }
  #pragma unroll
  for (int o = 1; o < 64; o <<= 1) v += __shfl_xor(v, o);
  float var = v * (1.0f / N1);
  float scv = rsqrtf(var + 1e-5f) * w[d];
  float sh = b_[d];
  for (int n = lane; n < N1; n += 64) {
    size_t id = ((size_t)bb * N1 + n) * DM + d;
    float nv = (X[id] - mu) * scv + sh;
    X[id] = nv;
    if (oH) {
      u16 hh = f2bf(nv);
      oH[id] = hh;
      oL[id] = f2bf(nv - bf2f(hh));
    }
  }
  if (lane == 0) {
    float hmean = ((s - g_old) * (1.0f / NN) - mu) * scv + sh;
    if (pool) pool[bb * DM + d] = hmean;
    if (do_g) X[((size_t)bb * N1 + NN) * DM + d] += hmean;
  }
}

// ---------------------------------------------------------------- p_multi + (h + pm) split emit
__global__ void pmadd_kernel(const float* __restrict__ X, const float* __restrict__ pools,
                             float* __restrict__ out_pm, u16* __restrict__ tH,
                             u16* __restrict__ tL) {
  int idx = blockIdx.x * 256 + threadIdx.x;
  if (idx >= BB * NN * DM) return;
  int d = idx % DM; int n = (idx / DM) % NN; int b = idx / (DM * NN);
  int pd = b * DM + d;
  float pmv = (pools[pd] + pools[BB * DM + pd] + pools[2 * BB * DM + pd]) * (1.0f / 3.0f);
  float v = X[((size_t)b * N1 + n) * DM + d] + pmv;
  u16 hh = f2bf(v);
  tH[idx] = hh;
  tL[idx] = f2bf(v - bf2f(hh));
  if (n == 0) out_pm[pd] = pmv;
}

// ================================================================ launch
extern "C" void kernel_launch(void* const* d_in, const int* in_sizes, int n_in,
                              void* d_out, int out_size, void* d_ws, size_t ws_size,
                              hipStream_t stream) {
  const float* coords = (const float*)d_in[0];
  const float* inW    = (const float*)d_in[1];
  const float* inb    = (const float*)d_in[2];
  const float* gnode  = (const float*)d_in[3];
  const float* Wq     = (const float*)d_in[4];
  const float* Wk     = (const float*)d_in[5];
  const float* Wv     = (const float*)d_in[6];
  const float* Wo     = (const float*)d_in[7];
  const float* emb    = (const float*)d_in[8];
  const float* W1     = (const float*)d_in[9];
  const float* b1     = (const float*)d_in[10];
  const float* W2     = (const float*)d_in[11];
  const float* b2     = (const float*)d_in[12];
  const float* n1w    = (const float*)d_in[13];
  const float* n1b    = (const float*)d_in[14];
  const float* n2w    = (const float*)d_in[15];
  const float* n2b    = (const float*)d_in[16];
  const float* outW   = (const float*)d_in[17];
  const float* outb   = (const float*)d_in[18];
  float* out = (float*)d_out;

  char* wsp = (char*)d_ws;
  size_t off = 0;
  auto alloc = [&](size_t bytes) -> void* {
    off = (off + 255) & ~(size_t)255;
    void* p = wsp + off;
    off += bytes;
    return p;
  };
  const size_t XB = (size_t)BB * N1 * DM * 4;       // fp32 activation buffer
  const size_t HB = (size_t)BB * N1 * DM * 2;       // u16 half buffer
  float* X0   = (float*)alloc(XB);
  float* X1   = (float*)alloc(XB);
  float* Qb   = (float*)alloc(XB);
  float* Yb   = (float*)alloc(XB);
  u16* XH = (u16*)alloc(HB); u16* XM = (u16*)alloc(HB); u16* XL = (u16*)alloc(HB);
  u16* QH = (u16*)alloc(HB); u16* QL = (u16*)alloc(HB);
  u16* KH = (u16*)alloc(HB); u16* KL = (u16*)alloc(HB);
  u16* Vbf = (u16*)alloc(HB);
  u16* CbH = (u16*)alloc(HB); u16* CbL = (u16*)alloc(HB);
  u16* YbH = (u16*)alloc(HB); u16* YbL = (u16*)alloc(HB);
  u16* FbH = (u16*)alloc((size_t)BB * N1 * DFF * 2);
  u16* FbL = (u16*)alloc((size_t)BB * N1 * DFF * 2);
  u16* tH = (u16*)alloc((size_t)BB * NN * DM * 2);
  u16* tL = (u16*)alloc((size_t)BB * NN * DM * 2);
  unsigned char* buckp = (unsigned char*)alloc((size_t)BB * N1 * BSTR);
  unsigned long long* adj = (unsigned long long*)alloc((size_t)BB * N1 * ADJW * 8);
  u32* connb = (u32*)alloc((size_t)BB * N1 * MW * 4);
  float* sqb   = (float*)alloc((size_t)BB * NN * 4);
  float* pools = (float*)alloc((size_t)NLAYERS * BB * DM * 4);
  float* qe_all = (float*)alloc((size_t)BB * NH * N1 * 32 * 4);
  float* ml = (float*)alloc((size_t)2 * BB * NH * NSPLIT * N1 * 4);
  u16* PH = (u16*)alloc((size_t)PW_TOT * 2);
  u16* PL = (u16*)alloc((size_t)PW_TOT * 2);
  float* scratch8 = (float*)alloc((size_t)BB * NH * NSPLIT * N1 * 16 * 4);  // >= d2 size

  float* d2 = scratch8;                    // gram keys (8.39 MB), dead before attn
  float* Opart = scratch8;                 // attn partials (8.40 MB)
  float* mpart = ml;
  float* lpart = ml + (size_t)BB * NH * NSPLIT * N1;

  prepack_kernel<<<296, 256, 0, stream>>>(Wq, Wk, Wv, Wo, W1, W2, outW, PH, PL);
  embed_kernel<<<(BB * N1 * DM + 255) / 256, 256, 0, stream>>>(coords, inW, inb, gnode, X0);
  bucket_kernel<<<(BB * N1 * BSTR + 255) / 256, 256, 0, stream>>>(coords, buckp);
  g_update_kernel<<<dim3(DM, BB), 64, 0, stream>>>(X0);   // layer 0 g-update

  float* Xin = X0; float* Xout = X1;
  const int M = BB * N1;
  const int GX = 33;     // ceil(129 m-tiles / 4 waves)
  for (int l = 0; l < NLAYERS; ++l) {
    xsplit_kernel<<<513, 256, 0, stream>>>(Xin, XH, XM, XL, sqb, adj);
    gram_kernel<<<dim3(32, 16, BB), 256, 0, stream>>>(XH, XM, XL, sqb, d2);
    knnsel_kernel<<<BB * NN / 4, 256, 0, stream>>>(d2, adj);
    connb_kernel<<<(BB * N1 + 255) / 256, 256, 0, stream>>>(adj, connb);

    gemm_qkv_kernel<<<dim3(GX, 8, 3), 256, 0, stream>>>(
        XH, XM,
        PH + PWQ_OFF + (size_t)l * DM * DM, PL + PWQ_OFF + (size_t)l * DM * DM,
        PH + PWK_OFF + (size_t)l * DM * DM, PL + PWK_OFF + (size_t)l * DM * DM,
        PH + PWV_OFF + (size_t)l * DM * DM, PL + PWV_OFF + (size_t)l * DM * DM,
        Qb, QH, QL, KH, KL, Vbf, M);
    qe_kernel<<<513, 256, 0, stream>>>(Qb, emb + (size_t)l * NBUK * DM, qe_all);

    attn_kernel<<<dim3(33, NH * BB, NSPLIT), 128, 0, stream>>>(
        QH, QL, KH, KL, Vbf, qe_all, buckp, connb, Opart, mpart, lpart);
    attn_combine_kernel<<<(BB * NH * N1 + 255) / 256, 256, 0, stream>>>(
        Opart, mpart, lpart, CbH, CbL);

    gemm_kernel<<<dim3(GX, 8), 256, 0, stream>>>(
        CbH, CbL, PH + PWO_OFF + (size_t)l * DM * DM, PL + PWO_OFF + (size_t)l * DM * DM,
        nullptr, Xin, Yb, nullptr, nullptr, M, DM, DM, 0);
    inorm_kernel<<<dim3(DM, BB), 64, 0, stream>>>(Yb, n1w + l * DM, n1b + l * DM,
                                                  nullptr, 0, YbH, YbL);

    gemm_kernel<<<dim3(GX, 32), 256, 0, stream>>>(
        YbH, YbL, PH + PW1_OFF + (size_t)l * DFF * DM, PL + PW1_OFF + (size_t)l * DFF * DM,
        b1 + l * DFF, nullptr, nullptr, FbH, FbL, M, DM, DFF, 1);
    gemm_kernel<<<dim3(GX, 8), 256, 0, stream>>>(
        FbH, FbL, PH + PW2_OFF + (size_t)l * DM * DFF, PL + PW2_OFF + (size_t)l * DM * DFF,
        b2 + l * DM, Yb, Xout, nullptr, nullptr, M, DFF, DM, 0);
    inorm_kernel<<<dim3(DM, BB), 64, 0, stream>>>(Xout, n2w + l * DM, n2b + l * DM,
                                                  pools + (size_t)l * BB * DM, 1,
                                                  nullptr, nullptr);

    float* t2 = Xin; Xin = Xout; Xout = t2;
  }

  pmadd_kernel<<<(BB * NN * DM + 255) / 256, 256, 0, stream>>>(
      Xin, pools, out + (size_t)BB * NN * DM, tH, tL);
  gemm_kernel<<<dim3(32, 8), 256, 0, stream>>>(
      tH, tL, PH + PWOUT_OFF, PL + PWOUT_OFF, outb, nullptr, out, nullptr, nullptr,
      BB * NN, DM, DM, 0);
}

// Round 10
// 547.837 us; speedup vs baseline: 1.3117x; 1.0420x over previous
//
#include <hip/hip_runtime.h>

#define BB 2
#define NN 1024
#define N1 1025
#define DM 128
#define NH 8
#define DK 16
#define DFF 512
#define NBUK 32
#define NLAYERS 3
#define KNN_K 10
#define ADJW 17          // 1025 bits -> 17 u64 words per row
#define MW 34            // 34 u32 mask words per row (1088 bits)
#define BSTR 1088        // padded bucket row stride (bytes)
#define NSPLIT 8
#define BIGF 3.0e38f
#define SM_OFF 24.0f     // fixed softmax exponent offset (|s| bounded << 24+88)

// prepacked-weight element offsets (see prepack_kernel)
#define PWQ_OFF 0
#define PWK_OFF 49152
#define PWV_OFF 98304
#define PWO_OFF 147456
#define PW1_OFF 196608
#define PW2_OFF 393216
#define PWOUT_OFF 589824
#define PWQE_OFF 606208
#define PW_TOT 704512

typedef __attribute__((ext_vector_type(8))) short bf8;
typedef __attribute__((ext_vector_type(4))) float f4;
typedef unsigned short u16;
typedef unsigned int u32;

__device__ __forceinline__ u16 f2bf(float x) {
  unsigned u = __float_as_uint(x);
  return (u16)((u + 0x7fff + ((u >> 16) & 1)) >> 16);   // RNE
}
__device__ __forceinline__ float bf2f(u16 u) {
  return __uint_as_float(((unsigned)u) << 16);
}
__device__ __forceinline__ bf8 mk8(ushort4 a, ushort4 b) {
  bf8 r;
  r[0] = (short)a.x; r[1] = (short)a.y; r[2] = (short)a.z; r[3] = (short)a.w;
  r[4] = (short)b.x; r[5] = (short)b.y; r[6] = (short)b.z; r[7] = (short)b.w;
  return r;
}

// ---------------------------------------------------------------- composite qe weight
// Wqe[(h,bk)][k] = sum_d emb[bk][h*16+d] * Wq[h*16+d][k]  (per layer, fp32)
__global__ void wqe_build_kernel(const float* __restrict__ Wq, const float* __restrict__ emb,
                                 float* __restrict__ Wqe) {
  int idx = blockIdx.x * 256 + threadIdx.x;
  if (idx >= NLAYERS * 256 * DM) return;
  int k = idx % DM; int c = (idx / DM) % 256; int l = idx / (DM * 256);
  int h = c >> 5, bk = c & 31;
  const float* wq = Wq + ((size_t)l * DM + h * DK) * DM;
  const float* e = emb + ((size_t)l * NBUK + bk) * DM + h * DK;
  float s = 0.f;
  #pragma unroll
  for (int d = 0; d < DK; ++d) s += e[d] * wq[(size_t)d * DM + k];
  Wqe[idx] = s;
}

// ---------------------------------------------------------------- weight prepack
// B-fragment layout: elem((nt,ks,lane,j)) = W[nt*16 + (lane&15)][ks*32 + (lane>>4)*8 + j]
__global__ void prepack_kernel(const float* __restrict__ Wq, const float* __restrict__ Wk,
                               const float* __restrict__ Wv, const float* __restrict__ Wo,
                               const float* __restrict__ W1, const float* __restrict__ W2,
                               const float* __restrict__ oW, const float* __restrict__ wqe,
                               u16* __restrict__ PH, u16* __restrict__ PL) {
  int idx = blockIdx.x * 256 + threadIdx.x;   // lane-group id (8 elems each)
  if (idx >= 88064) return;
  const float* W; int rel, Kdim;
  if (idx < 24576) {
    int seg = idx / 6144; rel = idx % 6144; Kdim = 128;
    W = seg == 0 ? Wq : seg == 1 ? Wk : seg == 2 ? Wv : Wo;
  } else if (idx < 49152) { rel = idx - 24576; Kdim = 128; W = W1; }
  else if (idx < 73728)   { rel = idx - 49152; Kdim = 512; W = W2; }
  else if (idx < 75776)   { rel = idx - 73728; Kdim = 128; W = oW; }
  else                    { rel = idx - 75776; Kdim = 128; W = wqe; }
  int lane = rel & 63;
  int g = rel >> 6;
  int ksteps = Kdim >> 5;
  int ks = g % ksteps, nt = g / ksteps;
  int n = nt * 16 + (lane & 15);
  int k = ks * 32 + (lane >> 4) * 8;
  const float* p = W + (size_t)n * Kdim + k;
  u16* ph = PH + (size_t)idx * 8;
  u16* pl = PL + (size_t)idx * 8;
  #pragma unroll
  for (int q = 0; q < 8; ++q) {
    float x = p[q];
    u16 hh = f2bf(x);
    ph[q] = hh;
    pl[q] = f2bf(x - bf2f(hh));
  }
}

// ---------------------------------------------------------------- embed
__global__ void embed_kernel(const float* __restrict__ coords, const float* __restrict__ inW,
                             const float* __restrict__ inb, const float* __restrict__ gnode,
                             float* __restrict__ X) {
  int idx = blockIdx.x * 256 + threadIdx.x;
  if (idx >= BB * N1 * DM) return;
  int d = idx % DM; int r = idx / DM; int n = r % N1; int b = r / N1;
  float v;
  if (n < NN) {
    float cx = coords[(b * NN + n) * 2 + 0], cy = coords[(b * NN + n) * 2 + 1];
    v = cx * inW[d * 2 + 0] + cy * inW[d * 2 + 1] + inb[d];
  } else {
    v = gnode[d];
  }
  X[idx] = v;
}

// ---------------------------------------------------------------- bucket (padded rows)
__global__ void bucket_kernel(const float* __restrict__ coords, unsigned char* __restrict__ buckp) {
  int idx = blockIdx.x * 256 + threadIdx.x;
  if (idx >= BB * N1 * BSTR) return;
  int j = idx % BSTR; int r = idx / BSTR; int i = r % N1; int b = r / N1;
  unsigned char v = 0;
  if (j < N1) {
    float xi = 0.f, yi = 0.f, xj = 0.f, yj = 0.f;
    if (i < NN) { xi = coords[(b * NN + i) * 2]; yi = coords[(b * NN + i) * 2 + 1]; }
    if (j < NN) { xj = coords[(b * NN + j) * 2]; yj = coords[(b * NN + j) * 2 + 1]; }
    float dx = xi - xj, dy = yi - yj;
    float dist = sqrtf(dx * dx + dy * dy);
    int bu = (int)(dist * 32.0f);
    bu = bu < 0 ? 0 : (bu > 31 ? 31 : bu);
    v = (unsigned char)bu;
  }
  buckp[idx] = v;
}

// ---------------------------------------------------------------- g += mean(h) (layer 0 only)
__global__ void g_update_kernel(float* __restrict__ X) {
  int d = blockIdx.x; int b = blockIdx.y; int lane = threadIdx.x;  // 64 threads
  float s = 0.f;
  for (int n = lane; n < NN; n += 64) s += X[((size_t)b * N1 + n) * DM + d];
  for (int o = 32; o; o >>= 1) s += __shfl_down(s, o);
  if (lane == 0) X[((size_t)b * N1 + NN) * DM + d] += s * (1.0f / NN);
}

// ---------------------------------------------------------------- X split (3-level exact) + rowsq + adj zero
__global__ __launch_bounds__(256) void xsplit_kernel(
    const float* __restrict__ X, u16* __restrict__ XH, u16* __restrict__ XM,
    u16* __restrict__ XL, float* __restrict__ sqb, unsigned long long* __restrict__ adj) {
  int t = threadIdx.x;
  int tid = blockIdx.x * 256 + t;
  if (tid < BB * N1 * ADJW) adj[tid] = 0ull;      // 513*256 = 131328 >= 34850
  int wave = blockIdx.x * 4 + (t >> 6), lane = t & 63;
  if (wave >= BB * N1) return;
  float2 v = *(const float2*)(X + (size_t)wave * DM + lane * 2);
  u16 h0 = f2bf(v.x); float r1 = v.x - bf2f(h0);
  u16 m0 = f2bf(r1);  u16 l0 = f2bf(r1 - bf2f(m0));
  u16 h1 = f2bf(v.y); float r2 = v.y - bf2f(h1);
  u16 m1 = f2bf(r2);  u16 l1 = f2bf(r2 - bf2f(m1));
  size_t o = (size_t)wave * DM + lane * 2;
  *(u32*)&XH[o] = (u32)h0 | ((u32)h1 << 16);
  *(u32*)&XM[o] = (u32)m0 | ((u32)m1 << 16);
  *(u32*)&XL[o] = (u32)l0 | ((u32)l1 << 16);
  float sq = v.x * v.x + v.y * v.y;
  #pragma unroll
  for (int oo = 1; oo < 64; oo <<= 1) sq += __shfl_xor(sq, oo);
  if (lane == 0) {
    int b = wave / N1, n = wave % N1;
    if (n < NN) sqb[b * NN + n] = sq;
  }
}

// ---------------------------------------------------------------- exact MFMA gram (3-level, prestaged)
__global__ __launch_bounds__(256) void gram_kernel(
    const u16* __restrict__ XH, const u16* __restrict__ XM, const u16* __restrict__ XL,
    const float* __restrict__ sqb, float* __restrict__ d2) {
  __shared__ __align__(16) u16 AsH[32][72];
  __shared__ __align__(16) u16 AsM[32][72];
  __shared__ __align__(16) u16 AsL[32][72];
  __shared__ __align__(16) u16 BsH[64][72];
  __shared__ __align__(16) u16 BsM[64][72];
  __shared__ __align__(16) u16 BsL[64][72];
  int b = blockIdx.z;
  int m0 = blockIdx.x * 32, n0 = blockIdx.y * 64;
  size_t boff = (size_t)b * N1;
  int t = threadIdx.x;
  int lane = t & 63, w = t >> 6;
  int wm = (w >> 1) * 16, wn = (w & 1) * 32;
  int quad = lane >> 4, r16 = lane & 15;

  f4 acc0 = {0.f, 0.f, 0.f, 0.f}, acc1 = {0.f, 0.f, 0.f, 0.f};
  int ar = t >> 3, as_ = (t & 7) * 8;     // A: 32 rows x 8 segs of 8
  int br = t >> 2, bs_ = (t & 3) * 16;    // B: 64 rows x 4 segs of 16

  for (int k0 = 0; k0 < DM; k0 += 64) {
    {
      size_t src = (boff + m0 + ar) * DM + k0 + as_;
      *(bf8*)&AsH[ar][as_] = *(const bf8*)(XH + src);
      *(bf8*)&AsM[ar][as_] = *(const bf8*)(XM + src);
      *(bf8*)&AsL[ar][as_] = *(const bf8*)(XL + src);
    }
    {
      size_t src = (boff + n0 + br) * DM + k0 + bs_;
      *(bf8*)&BsH[br][bs_] = *(const bf8*)(XH + src);
      *(bf8*)&BsH[br][bs_ + 8] = *(const bf8*)(XH + src + 8);
      *(bf8*)&BsM[br][bs_] = *(const bf8*)(XM + src);
      *(bf8*)&BsM[br][bs_ + 8] = *(const bf8*)(XM + src + 8);
      *(bf8*)&BsL[br][bs_] = *(const bf8*)(XL + src);
      *(bf8*)&BsL[br][bs_ + 8] = *(const bf8*)(XL + src + 8);
    }
    __syncthreads();
    #pragma unroll
    for (int ks = 0; ks < 64; ks += 16) {
      int seg = (quad & 1) * 8;
      bf8 aHM = *(const bf8*)((quad < 2) ? &AsH[wm + r16][ks + seg] : &AsM[wm + r16][ks + seg]);
      bf8 aHL = *(const bf8*)((quad < 2) ? &AsH[wm + r16][ks + seg] : &AsL[wm + r16][ks + seg]);
      #pragma unroll
      for (int tt = 0; tt < 2; ++tt) {
        int nr = wn + tt * 16 + r16;
        bf8 bH = *(const bf8*)&BsH[nr][ks + seg];
        bf8 bM = *(const bf8*)&BsM[nr][ks + seg];
        bf8 b3 = *(const bf8*)((quad < 2) ? &BsL[nr][ks + seg] : &BsH[nr][ks + seg]);
        f4& a = tt ? acc1 : acc0;
        a = __builtin_amdgcn_mfma_f32_16x16x32_bf16(aHM, bH, a, 0, 0, 0);  // HH' + MH'
        a = __builtin_amdgcn_mfma_f32_16x16x32_bf16(aHM, bM, a, 0, 0, 0);  // HM' + MM'
        a = __builtin_amdgcn_mfma_f32_16x16x32_bf16(aHL, b3, a, 0, 0, 0);  // HL' + LH'
      }
    }
    __syncthreads();
  }

  #pragma unroll
  for (int tt = 0; tt < 2; ++tt) {
    f4 a = tt ? acc1 : acc0;
    int n = n0 + wn + tt * 16 + r16;
    float sj = sqb[b * NN + n];
    #pragma unroll
    for (int reg = 0; reg < 4; ++reg) {
      int m = m0 + wm + quad * 4 + reg;
      float si = sqb[b * NN + m];
      float v = (m == n) ? BIGF : (si + sj - 2.f * a[reg]);
      d2[((size_t)b * NN + m) * NN + n] = v;
    }
  }
}

// ---------------------------------------------------------------- top-10 select -> adjacency bits
__global__ __launch_bounds__(256) void knnsel_kernel(const float* __restrict__ d2,
                                                     unsigned long long* __restrict__ adj) {
  __shared__ float dd[4][NN];
  int blk = blockIdx.x;
  int b = blk / (NN / 4);
  int i0 = (blk % (NN / 4)) * 4;
  int t = threadIdx.x, lane = t & 63, w = t >> 6;

  const float4* src = (const float4*)(d2 + ((size_t)b * NN + i0) * NN);
  float4* dst = (float4*)&dd[0][0];
  #pragma unroll
  for (int x = 0; x < 4; ++x) dst[t + x * 256] = src[t + x * 256];
  __syncthreads();

  int i = i0 + w;
  for (int it = 0; it < KNN_K; ++it) {
    float bv = BIGF; int bi = 0x3fffffff;
    for (int j = lane; j < NN; j += 64) {
      float v = dd[w][j];
      if (v < bv) { bv = v; bi = j; }
    }
    #pragma unroll
    for (int o = 1; o < 64; o <<= 1) {
      float ov = __shfl_xor(bv, o); int oi = __shfl_xor(bi, o);
      if (ov < bv || (ov == bv && oi < bi)) { bv = ov; bi = oi; }
    }
    if (lane == 0) {
      dd[w][bi] = BIGF;
      atomicOr(&adj[((size_t)b * N1 + i) * ADJW + (bi >> 6)], 1ull << (bi & 63));
      atomicOr(&adj[((size_t)b * N1 + bi) * ADJW + (i >> 6)], 1ull << (i & 63));
    }
  }
}

// ---------------------------------------------------------------- conn bitmask build
__global__ void connb_kernel(const unsigned long long* __restrict__ adj,
                             u32* __restrict__ connb) {
  int idx = blockIdx.x * 256 + threadIdx.x;
  if (idx >= BB * N1) return;
  int b = idx / N1, i = idx % N1;
  const u32* arow = (const u32*)(adj + (size_t)(b * N1 + i) * ADJW);
  u32* crow = connb + (size_t)(b * N1 + i) * MW;
  bool allv = (i == 0 || i == NN);
  int lo = 0, hi = -1;
  if (i < NN) {
    int bs = i & ~127;
    lo = i - 11 < bs ? bs : i - 11;
    int be = bs + 127;
    hi = i + 11 > be ? be : i + 11;
  }
  for (int w = 0; w < MW; ++w) {
    u32 v;
    if (allv) {
      v = 0xffffffffu;
    } else {
      v = arow[w];
      int a = lo - 32 * w, bnd = hi - 32 * w;
      if (a < 0) a = 0; if (bnd > 31) bnd = 31;
      if (a <= bnd) v |= (0xffffffffu << a) & (0xffffffffu >> (31 - bnd));
      if (w == 0) v |= 1u;
      if (w == 32) v |= 1u;
      int dg = i - 32 * w;
      if (dg >= 0 && dg < 32) v |= 1u << dg;
    }
    if (w == 32) v &= 1u;
    else if (w == 33) v = 0u;
    crow[w] = v;
  }
}

// ---------------------------------------------------------------- direct-fragment GEMM (16x16/wave)
__device__ __forceinline__ void gemm_dev16(
    const u16* __restrict__ AH, const u16* __restrict__ AL,
    const u16* __restrict__ PH, const u16* __restrict__ PL,
    const float* __restrict__ bias, const float* __restrict__ res,
    float* __restrict__ outF, u16* __restrict__ outH, u16* __restrict__ outL,
    int M, int Kdim, int Nout, int relu, int mt, int nt) {
  int lane = threadIdx.x & 63;
  int quad = lane >> 4, r16 = lane & 15;
  int ksteps = Kdim >> 5;
  f4 acc = {0.f, 0.f, 0.f, 0.f};

  int m0 = mt * 16;
  int mrow = m0 + r16; if (mrow >= M) mrow = M - 1;   // clamp; result discarded
  const u16* aph = AH + (size_t)mrow * Kdim + quad * 8;
  const u16* apl = AL + (size_t)mrow * Kdim + quad * 8;
  const u16* ph = PH + ((size_t)nt * ksteps * 64 + lane) * 8;
  const u16* pl = PL + ((size_t)nt * ksteps * 64 + lane) * 8;

  #pragma unroll 4
  for (int ks = 0; ks < ksteps; ++ks) {
    bf8 aH = *(const bf8*)(aph);
    bf8 aL = *(const bf8*)(apl);
    aph += 32; apl += 32;
    bf8 bH = *(const bf8*)(ph + (size_t)ks * 512);
    bf8 bL = *(const bf8*)(pl + (size_t)ks * 512);
    acc = __builtin_amdgcn_mfma_f32_16x16x32_bf16(aH, bH, acc, 0, 0, 0);
    acc = __builtin_amdgcn_mfma_f32_16x16x32_bf16(aH, bL, acc, 0, 0, 0);
    acc = __builtin_amdgcn_mfma_f32_16x16x32_bf16(aL, bH, acc, 0, 0, 0);
  }

  if (m0 >= M) return;
  int n = nt * 16 + r16;
  #pragma unroll
  for (int reg = 0; reg < 4; ++reg) {
    int m = m0 + quad * 4 + reg;    // C layout: col=lane&15, row=quad*4+reg
    if (m < M) {
      float v = acc[reg];
      if (bias) v += bias[n];
      if (relu) v = fmaxf(v, 0.f);
      if (res) v += res[(size_t)m * Nout + n];
      size_t oi = (size_t)m * Nout + n;
      if (outF) outF[oi] = v;
      if (outH) {
        u16 hh = f2bf(v);
        outH[oi] = hh;
        outL[oi] = f2bf(v - bf2f(hh));
      }
    }
  }
}

__global__ __launch_bounds__(256) void gemm_kernel(
    const u16* __restrict__ AH, const u16* __restrict__ AL,
    const u16* __restrict__ PH, const u16* __restrict__ PL,
    const float* __restrict__ bias, const float* __restrict__ res,
    float* __restrict__ outF, u16* __restrict__ outH, u16* __restrict__ outL,
    int M, int Kdim, int Nout, int relu) {
  gemm_dev16(AH, AL, PH, PL, bias, res, outF, outH, outL, M, Kdim, Nout, relu,
             blockIdx.x * 4 + (threadIdx.x >> 6), blockIdx.y);
}

// QKV+QE: z=0 Q (0.25-scaled split), z=1 K (split), z=2 V (bf16), z=3 qe (fp32, composite W)
__global__ __launch_bounds__(256) void gemm_qkv_kernel(
    const u16* __restrict__ AH, const u16* __restrict__ AL,
    const u16* __restrict__ Pbase_H, const u16* __restrict__ Pbase_L,
    size_t offQ, size_t offK, size_t offV, size_t offE,
    u16* __restrict__ QH, u16* __restrict__ QL,
    u16* __restrict__ KH, u16* __restrict__ KL, u16* __restrict__ Vbf,
    float* __restrict__ qe_all, int M) {
  int z = blockIdx.z;
  int nt = blockIdx.y;
  if (z != 3 && nt >= 8) return;
  size_t woff = z == 0 ? offQ : (z == 1 ? offK : (z == 2 ? offV : offE));
  const u16* PH = Pbase_H + woff;
  const u16* PL = Pbase_L + woff;
  int lane = threadIdx.x & 63;
  int quad = lane >> 4, r16 = lane & 15;
  int mt = blockIdx.x * 4 + (threadIdx.x >> 6);
  f4 acc = {0.f, 0.f, 0.f, 0.f};
  int m0 = mt * 16;
  int mrow = m0 + r16; if (mrow >= M) mrow = M - 1;
  const u16* aph = AH + (size_t)mrow * DM + quad * 8;
  const u16* apl = AL + (size_t)mrow * DM + quad * 8;
  const u16* ph = PH + ((size_t)nt * 4 * 64 + lane) * 8;
  const u16* pl = PL + ((size_t)nt * 4 * 64 + lane) * 8;
  #pragma unroll
  for (int ks = 0; ks < 4; ++ks) {
    bf8 aH = *(const bf8*)(aph);
    bf8 aL = *(const bf8*)(apl);
    aph += 32; apl += 32;
    bf8 bH = *(const bf8*)(ph + (size_t)ks * 512);
    bf8 bL = *(const bf8*)(pl + (size_t)ks * 512);
    acc = __builtin_amdgcn_mfma_f32_16x16x32_bf16(aH, bH, acc, 0, 0, 0);
    acc = __builtin_amdgcn_mfma_f32_16x16x32_bf16(aH, bL, acc, 0, 0, 0);
    acc = __builtin_amdgcn_mfma_f32_16x16x32_bf16(aL, bH, acc, 0, 0, 0);
  }
  if (m0 >= M) return;
  int n = nt * 16 + r16;
  #pragma unroll
  for (int reg = 0; reg < 4; ++reg) {
    int m = m0 + quad * 4 + reg;
    if (m >= M) continue;
    float v = acc[reg];
    if (z == 3) {
      int b = m / N1, nr = m % N1;
      int h = n >> 5, bk = n & 31;
      qe_all[(((size_t)b * NH + h) * N1 + nr) * 32 + bk] = v;
      continue;
    }
    size_t oi = (size_t)m * DM + n;
    if (z == 0) {
      float sv = v * 0.25f;
      u16 hh = f2bf(sv);
      QH[oi] = hh;
      QL[oi] = f2bf(sv - bf2f(hh));
    } else if (z == 1) {
      u16 hh = f2bf(v);
      KH[oi] = hh;
      KL[oi] = f2bf(v - bf2f(hh));
    } else {
      Vbf[oi] = f2bf(v);
    }
  }
}

// ---------------------------------------------------------------- MFMA flash attention, key-split
// Fixed-offset softmax: p = exp(s - SM_OFF); no running max, no rescale. Masked -> exp(-1e9)=0.
#define CH 64
#define NCH 17
__global__ __launch_bounds__(128) void attn_kernel(
    const u16* __restrict__ QH, const u16* __restrict__ QL,
    const u16* __restrict__ KH, const u16* __restrict__ KL,
    const u16* __restrict__ Vbf, const float* __restrict__ qe_all,
    const unsigned char* __restrict__ buckp, const u32* __restrict__ connb,
    float* __restrict__ Opart, float* __restrict__ lpart) {
  __shared__ __align__(16) u16 KsHi[2][CH][20];
  __shared__ __align__(16) u16 KsLo[2][CH][20];
  __shared__ __align__(16) u16 Vt[2][DK][68];
  __shared__ __align__(16) u16 Ps[2][16][72];
  __shared__ __align__(16) float qe_s[2][16][36];
  __shared__ u32 maskS[32][6];
  __shared__ unsigned char buckS[2][32][68];

  int qt = blockIdx.x;
  int h = blockIdx.y & 7, b = blockIdx.y >> 3;
  int s = blockIdx.z;
  int c0 = (NCH * s) / NSPLIT, c1 = (NCH * (s + 1)) / NSPLIT;
  int nwm = 2 * (c1 - c0);
  int t = threadIdx.x, lane = t & 63, w = t >> 6;
  int quad = lane >> 4, r16 = lane & 15;
  int i0 = qt * 32;
  int iw = i0 + w * 16;
  int bh = b * NH + h;

  for (int x = t; x < 32 * nwm; x += 128) {
    int rr = x / nwm, ww = x % nwm;
    int gi = i0 + rr; if (gi > NN) gi = NN;
    maskS[rr][ww] = connb[((size_t)b * N1 + gi) * MW + 2 * c0 + ww];
  }
  // qe table: per-row clamped load
  #pragma unroll
  for (int e = 0; e < 2; ++e) {
    int x = lane + e * 64;
    int rr = x >> 3, bk = (x & 7) * 4;
    int gi = iw + rr; if (gi > NN) gi = NN;
    f4 v = *(const f4*)(qe_all + (((size_t)b * NH + h) * N1 + gi) * 32 + bk);
    *(f4*)&qe_s[w][rr][bk] = v;
  }
  bf8 qfrag;
  {
    int gi = iw + r16; if (gi > NN) gi = NN;
    const u16* qsrc = (quad < 2 ? QH : QL) + ((size_t)(b * N1 + gi) * DM + h * DK + (quad & 1) * 8);
    qfrag = *(const bf8*)qsrc;
  }

  ushort4 khr[2], klr[2], vvr[2]; u32 bkr[4];
  auto load_chunk = [&](int c) {
    int j0 = c * CH;
    #pragma unroll
    for (int ii = 0; ii < 2; ++ii) {
      int x = t + ii * 128;
      int key = x >> 2, ds = (x & 3) * 4;
      int jg = j0 + key; if (jg > NN) jg = NN;
      size_t src = (size_t)(b * N1 + jg) * DM + h * DK + ds;
      khr[ii] = *(const ushort4*)(KH + src);
      klr[ii] = *(const ushort4*)(KL + src);
      vvr[ii] = *(const ushort4*)(Vbf + src);
    }
    #pragma unroll
    for (int ii = 0; ii < 4; ++ii) {
      int x = t + ii * 128;
      int rr = x >> 4, c4 = (x & 15) * 4;
      int gi = i0 + rr; if (gi > NN) gi = NN;
      bkr[ii] = *(const u32*)(buckp + ((size_t)b * N1 + gi) * BSTR + j0 + c4);
    }
  };
  auto store_chunk = [&](int pb) {
    #pragma unroll
    for (int ii = 0; ii < 2; ++ii) {
      int x = t + ii * 128;
      int key = x >> 2, ds = (x & 3) * 4;
      *(ushort4*)&KsHi[pb][key][ds] = khr[ii];
      *(ushort4*)&KsLo[pb][key][ds] = klr[ii];
      Vt[pb][ds + 0][key] = vvr[ii].x;
      Vt[pb][ds + 1][key] = vvr[ii].y;
      Vt[pb][ds + 2][key] = vvr[ii].z;
      Vt[pb][ds + 3][key] = vvr[ii].w;
    }
    #pragma unroll
    for (int ii = 0; ii < 4; ++ii) {
      int x = t + ii * 128;
      int rr = x >> 4, c4 = (x & 15) * 4;
      *(u32*)&buckS[pb][rr][c4] = bkr[ii];
    }
  };

  f4 Oacc = {0.f, 0.f, 0.f, 0.f};
  float lrun[4] = {0.f, 0.f, 0.f, 0.f};

  load_chunk(c0);
  store_chunk(0);

  for (int c = c0; c < c1; ++c) {
    int pb = (c - c0) & 1;
    bool pf = (c + 1 < c1);
    if (pf) load_chunk(c + 1);
    __syncthreads();

    f4 S[4];
    #pragma unroll
    for (int tt = 0; tt < 4; ++tt) {
      int key = tt * 16 + r16;
      int off = (quad & 1) * 8;
      bf8 bhv = mk8(*(const ushort4*)&KsHi[pb][key][off], *(const ushort4*)&KsHi[pb][key][off + 4]);
      bf8 blv = mk8(*(const ushort4*)&KsLo[pb][key][off], *(const ushort4*)&KsLo[pb][key][off + 4]);
      f4 z = {0.f, 0.f, 0.f, 0.f};
      z = __builtin_amdgcn_mfma_f32_16x16x32_bf16(qfrag, bhv, z, 0, 0, 0);
      z = __builtin_amdgcn_mfma_f32_16x16x32_bf16(qfrag, blv, z, 0, 0, 0);
      S[tt] = z;
    }

    #pragma unroll
    for (int rg = 0; rg < 4; ++rg) {
      int rowb = w * 16 + quad * 4 + rg;
      u32 mw0 = maskS[rowb][2 * (c - c0)];
      u32 mw1 = maskS[rowb][2 * (c - c0) + 1];
      float ps = 0.f;
      #pragma unroll
      for (int tt = 0; tt < 4; ++tt) {
        u32 mword = (tt & 2) ? mw1 : mw0;
        int bit = (tt & 1) * 16 + r16;
        int bk = buckS[pb][rowb][tt * 16 + r16] & 31;
        float rel = qe_s[w][quad * 4 + rg][bk];
        float sc = S[tt][rg] + rel;
        sc += ((mword >> bit) & 1u) ? 0.f : -1.0e9f;
        float p = __expf(sc - SM_OFF);
        ps += p;
        Ps[w][quad * 4 + rg][tt * 16 + r16] = f2bf(p);
      }
      #pragma unroll
      for (int o = 1; o < 16; o <<= 1) ps += __shfl_xor(ps, o);
      lrun[rg] += ps;
    }
    #pragma unroll
    for (int half = 0; half < 2; ++half) {
      bf8 pa = *(const bf8*)&Ps[w][r16][half * 32 + quad * 8];
      bf8 vb = mk8(*(const ushort4*)&Vt[pb][r16][half * 32 + quad * 8],
                   *(const ushort4*)&Vt[pb][r16][half * 32 + quad * 8 + 4]);
      Oacc = __builtin_amdgcn_mfma_f32_16x16x32_bf16(pa, vb, Oacc, 0, 0, 0);
    }

    if (pf) store_chunk(pb ^ 1);
  }

  #pragma unroll
  for (int rg = 0; rg < 4; ++rg) {
    int gi = i0 + w * 16 + quad * 4 + rg;
    if (gi < N1) {
      size_t base = ((size_t)(bh * NSPLIT + s) * N1 + gi);
      Opart[base * 16 + r16] = Oacc[rg];
      if (r16 == 0) lpart[base] = lrun[rg];
    }
  }
}

// ---------------------------------------------------------------- combine split partials (plain sums)
__global__ void attn_combine_kernel(const float* __restrict__ Opart,
                                    const float* __restrict__ lpart,
                                    u16* __restrict__ CbH, u16* __restrict__ CbL) {
  int idx = blockIdx.x * 256 + threadIdx.x;
  if (idx >= BB * NH * N1) return;
  int q = idx % N1; int bh = idx / N1; int h = bh & 7; int b = bh >> 3;
  float l = 0.f;
  float o[16];
  #pragma unroll
  for (int d = 0; d < DK; ++d) o[d] = 0.f;
  #pragma unroll
  for (int s = 0; s < NSPLIT; ++s) {
    size_t base = (size_t)(bh * NSPLIT + s) * N1 + q;
    l += lpart[base];
    const float* op = Opart + base * 16;
    #pragma unroll
    for (int d = 0; d < DK; ++d) o[d] += op[d];
  }
  float inv = 1.0f / l;
  size_t obase = ((size_t)b * N1 + q) * DM + h * DK;
  #pragma unroll
  for (int d = 0; d < DK; ++d) {
    float v = o[d] * inv;
    u16 hh = f2bf(v);
    CbH[obase + d] = hh;
    CbL[obase + d] = f2bf(v - bf2f(hh));
  }
}

// ---------------------------------------------------------------- instance norm (+pool/g, +split emit)
__global__ void inorm_kernel(float* __restrict__ X, const float* __restrict__ w,
                             const float* __restrict__ b_, float* __restrict__ pool,
                             int do_g, u16* __restrict__ oH, u16* __restrict__ oL) {
  int d = blockIdx.x; int bb = blockIdx.y; int lane = threadIdx.x;
  float g_old = X[((size_t)bb * N1 + NN) * DM + d];
  float s = 0.f;
  for (int n = lane; n < N1; n += 64) s += X[((size_t)bb * N1 + n) * DM + d];
  #pragma unroll
  for (int o = 1; o < 64; o <<= 1) s += __shfl_xor(s, o);
  float mu = s * (1.0f / N1);
  float v = 0.f;
  for (int n = lane; n < N1; n += 64) {
    float tt = X[((size_t)bb * N1 + n) * DM + d] - mu;
    v += tt * tt;
  }
  #pragma unroll
  for (int o = 1; o < 64; o <<= 1) v += __shfl_xor(v, o);
  float var = v * (1.0f / N1);
  float scv = rsqrtf(var + 1e-5f) * w[d];
  float sh = b_[d];
  for (int n = lane; n < N1; n += 64) {
    size_t id = ((size_t)bb * N1 + n) * DM + d;
    float nv = (X[id] - mu) * scv + sh;
    X[id] = nv;
    if (oH) {
      u16 hh = f2bf(nv);
      oH[id] = hh;
      oL[id] = f2bf(nv - bf2f(hh));
    }
  }
  if (lane == 0) {
    float hmean = ((s - g_old) * (1.0f / NN) - mu) * scv + sh;
    if (pool) pool[bb * DM + d] = hmean;
    if (do_g) X[((size_t)bb * N1 + NN) * DM + d] += hmean;
  }
}

// ---------------------------------------------------------------- p_multi + (h + pm) split emit
__global__ void pmadd_kernel(const float* __restrict__ X, const float* __restrict__ pools,
                             float* __restrict__ out_pm, u16* __restrict__ tH,
                             u16* __restrict__ tL) {
  int idx = blockIdx.x * 256 + threadIdx.x;
  if (idx >= BB * NN * DM) return;
  int d = idx % DM; int n = (idx / DM) % NN; int b = idx / (DM * NN);
  int pd = b * DM + d;
  float pmv = (pools[pd] + pools[BB * DM + pd] + pools[2 * BB * DM + pd]) * (1.0f / 3.0f);
  float v = X[((size_t)b * N1 + n) * DM + d] + pmv;
  u16 hh = f2bf(v);
  tH[idx] = hh;
  tL[idx] = f2bf(v - bf2f(hh));
  if (n == 0) out_pm[pd] = pmv;
}

// ================================================================ launch
extern "C" void kernel_launch(void* const* d_in, const int* in_sizes, int n_in,
                              void* d_out, int out_size, void* d_ws, size_t ws_size,
                              hipStream_t stream) {
  const float* coords = (const float*)d_in[0];
  const float* inW    = (const float*)d_in[1];
  const float* inb    = (const float*)d_in[2];
  const float* gnode  = (const float*)d_in[3];
  const float* Wq     = (const float*)d_in[4];
  const float* Wk     = (const float*)d_in[5];
  const float* Wv     = (const float*)d_in[6];
  const float* Wo     = (const float*)d_in[7];
  const float* emb    = (const float*)d_in[8];
  const float* W1     = (const float*)d_in[9];
  const float* b1     = (const float*)d_in[10];
  const float* W2     = (const float*)d_in[11];
  const float* b2     = (const float*)d_in[12];
  const float* n1w    = (const float*)d_in[13];
  const float* n1b    = (const float*)d_in[14];
  const float* n2w    = (const float*)d_in[15];
  const float* n2b    = (const float*)d_in[16];
  const float* outW   = (const float*)d_in[17];
  const float* outb   = (const float*)d_in[18];
  float* out = (float*)d_out;

  char* wsp = (char*)d_ws;
  size_t off = 0;
  auto alloc = [&](size_t bytes) -> void* {
    off = (off + 255) & ~(size_t)255;
    void* p = wsp + off;
    off += bytes;
    return p;
  };
  const size_t XB = (size_t)BB * N1 * DM * 4;       // fp32 activation buffer
  const size_t HB = (size_t)BB * N1 * DM * 2;       // u16 half buffer
  float* X0   = (float*)alloc(XB);
  float* X1   = (float*)alloc(XB);
  float* Yb   = (float*)alloc(XB);
  u16* XH = (u16*)alloc(HB); u16* XM = (u16*)alloc(HB); u16* XL = (u16*)alloc(HB);
  u16* QH = (u16*)alloc(HB); u16* QL = (u16*)alloc(HB);
  u16* KH = (u16*)alloc(HB); u16* KL = (u16*)alloc(HB);
  u16* Vbf = (u16*)alloc(HB);
  u16* CbH = (u16*)alloc(HB); u16* CbL = (u16*)alloc(HB);
  u16* YbH = (u16*)alloc(HB); u16* YbL = (u16*)alloc(HB);
  u16* FbH = (u16*)alloc((size_t)BB * N1 * DFF * 2);
  u16* FbL = (u16*)alloc((size_t)BB * N1 * DFF * 2);
  u16* tH = (u16*)alloc((size_t)BB * NN * DM * 2);
  u16* tL = (u16*)alloc((size_t)BB * NN * DM * 2);
  unsigned char* buckp = (unsigned char*)alloc((size_t)BB * N1 * BSTR);
  unsigned long long* adj = (unsigned long long*)alloc((size_t)BB * N1 * ADJW * 8);
  u32* connb = (u32*)alloc((size_t)BB * N1 * MW * 4);
  float* sqb   = (float*)alloc((size_t)BB * NN * 4);
  float* pools = (float*)alloc((size_t)NLAYERS * BB * DM * 4);
  float* qe_all = (float*)alloc((size_t)BB * NH * N1 * 32 * 4);
  float* lpart = (float*)alloc((size_t)BB * NH * NSPLIT * N1 * 4);
  float* wqeS = (float*)alloc((size_t)NLAYERS * 256 * DM * 4);
  u16* PH = (u16*)alloc((size_t)PW_TOT * 2);
  u16* PL = (u16*)alloc((size_t)PW_TOT * 2);
  float* scratch8 = (float*)alloc((size_t)BB * NH * NSPLIT * N1 * 16 * 4);  // >= d2 size

  float* d2 = scratch8;                    // gram keys (8.39 MB), dead before attn
  float* Opart = scratch8;                 // attn partials (8.40 MB)

  wqe_build_kernel<<<(NLAYERS * 256 * DM + 255) / 256, 256, 0, stream>>>(Wq, emb, wqeS);
  prepack_kernel<<<(88064 + 255) / 256, 256, 0, stream>>>(Wq, Wk, Wv, Wo, W1, W2, outW, wqeS, PH, PL);
  embed_kernel<<<(BB * N1 * DM + 255) / 256, 256, 0, stream>>>(coords, inW, inb, gnode, X0);
  bucket_kernel<<<(BB * N1 * BSTR + 255) / 256, 256, 0, stream>>>(coords, buckp);
  g_update_kernel<<<dim3(DM, BB), 64, 0, stream>>>(X0);   // layer 0 g-update

  float* Xin = X0; float* Xout = X1;
  const int M = BB * N1;
  const int GX = 33;     // ceil(129 m-tiles / 4 waves)
  for (int l = 0; l < NLAYERS; ++l) {
    xsplit_kernel<<<513, 256, 0, stream>>>(Xin, XH, XM, XL, sqb, adj);
    gram_kernel<<<dim3(32, 16, BB), 256, 0, stream>>>(XH, XM, XL, sqb, d2);
    knnsel_kernel<<<BB * NN / 4, 256, 0, stream>>>(d2, adj);
    connb_kernel<<<(BB * N1 + 255) / 256, 256, 0, stream>>>(adj, connb);

    gemm_qkv_kernel<<<dim3(GX, 16, 4), 256, 0, stream>>>(
        XH, XM, PH, PL,
        (size_t)PWQ_OFF + (size_t)l * DM * DM,
        (size_t)PWK_OFF + (size_t)l * DM * DM,
        (size_t)PWV_OFF + (size_t)l * DM * DM,
        (size_t)PWQE_OFF + (size_t)l * 256 * DM,
        QH, QL, KH, KL, Vbf, qe_all, M);

    attn_kernel<<<dim3(33, NH * BB, NSPLIT), 128, 0, stream>>>(
        QH, QL, KH, KL, Vbf, qe_all, buckp, connb, Opart, lpart);
    attn_combine_kernel<<<(BB * NH * N1 + 255) / 256, 256, 0, stream>>>(
        Opart, lpart, CbH, CbL);

    gemm_kernel<<<dim3(GX, 8), 256, 0, stream>>>(
        CbH, CbL, PH + PWO_OFF + (size_t)l * DM * DM, PL + PWO_OFF + (size_t)l * DM * DM,
        nullptr, Xin, Yb, nullptr, nullptr, M, DM, DM, 0);
    inorm_kernel<<<dim3(DM, BB), 64, 0, stream>>>(Yb, n1w + l * DM, n1b + l * DM,
                                                  nullptr, 0, YbH, YbL);

    gemm_kernel<<<dim3(GX, 32), 256, 0, stream>>>(
        YbH, YbL, PH + PW1_OFF + (size_t)l * DFF * DM, PL + PW1_OFF + (size_t)l * DFF * DM,
        b1 + l * DFF, nullptr, nullptr, FbH, FbL, M, DM, DFF, 1);
    gemm_kernel<<<dim3(GX, 8), 256, 0, stream>>>(
        FbH, FbL, PH + PW2_OFF + (size_t)l * DM * DFF, PL + PW2_OFF + (size_t)l * DM * DFF,
        b2 + l * DM, Yb, Xout, nullptr, nullptr, M, DFF, DM, 0);
    inorm_kernel<<<dim3(DM, BB), 64, 0, stream>>>(Xout, n2w + l * DM, n2b + l * DM,
                                                  pools + (size_t)l * BB * DM, 1,
                                                  nullptr, nullptr);

    float* t2 = Xin; Xin = Xout; Xout = t2;
  }

  pmadd_kernel<<<(BB * NN * DM + 255) / 256, 256, 0, stream>>>(
      Xin, pools, out + (size_t)BB * NN * DM, tH, tL);
  gemm_kernel<<<dim3(32, 8), 256, 0, stream>>>(
      tH, tL, PH + PWOUT_OFF, PL + PWOUT_OFF, outb, nullptr, out, nullptr, nullptr,
      BB * NN, DM, DM, 0);
}

// Round 11
// 512.032 us; speedup vs baseline: 1.4034x; 1.0699x over previous
//
#include <hip/hip_runtime.h>

#define BB 2
#define NN 1024
#define N1 1025
#define DM 128
#define NH 8
#define DK 16
#define DFF 512
#define NBUK 32
#define NLAYERS 3
#define KNN_K 10
#define ADJW 17          // 1025 bits -> 17 u64 words per row
#define BSTR 1088        // padded bucket row stride (bytes)
#define NSPLIT 8
#define BIGF 3.0e38f
#define SM_OFF 24.0f     // fixed softmax exponent offset (|s| bounded << 24+88)

// prepacked-weight element offsets (see prepack_kernel)
#define PWQ_OFF 0
#define PWK_OFF 49152
#define PWV_OFF 98304
#define PWO_OFF 147456
#define PW1_OFF 196608
#define PW2_OFF 393216
#define PWOUT_OFF 589824
#define PWQE_OFF 606208
#define PW_TOT 704512

typedef __attribute__((ext_vector_type(8))) short bf8;
typedef __attribute__((ext_vector_type(4))) float f4;
typedef unsigned short u16;
typedef unsigned int u32;

__device__ __forceinline__ u16 f2bf(float x) {
  unsigned u = __float_as_uint(x);
  return (u16)((u + 0x7fff + ((u >> 16) & 1)) >> 16);   // RNE
}
__device__ __forceinline__ float bf2f(u16 u) {
  return __uint_as_float(((unsigned)u) << 16);
}
__device__ __forceinline__ bf8 mk8(ushort4 a, ushort4 b) {
  bf8 r;
  r[0] = (short)a.x; r[1] = (short)a.y; r[2] = (short)a.z; r[3] = (short)a.w;
  r[4] = (short)b.x; r[5] = (short)b.y; r[6] = (short)b.z; r[7] = (short)b.w;
  return r;
}

// ---------------------------------------------------------------- weight prepack (+inline wqe)
// B-fragment layout: elem((nt,ks,lane,j)) = W[nt*16 + (lane&15)][ks*32 + (lane>>4)*8 + j]
__global__ void prepack_kernel(const float* __restrict__ Wq, const float* __restrict__ Wk,
                               const float* __restrict__ Wv, const float* __restrict__ Wo,
                               const float* __restrict__ W1, const float* __restrict__ W2,
                               const float* __restrict__ oW, const float* __restrict__ emb,
                               u16* __restrict__ PH, u16* __restrict__ PL) {
  int idx = blockIdx.x * 256 + threadIdx.x;   // lane-group id (8 elems each)
  if (idx >= 88064) return;
  if (idx >= 75776) {
    // composite qe weight: Wqe[(l,h,bk)][k] = sum_d emb[l][bk][h*16+d] * Wq[l][h*16+d][k]
    int rel = idx - 75776;
    int lane = rel & 63, g = rel >> 6;
    int ks = g & 3, nt = g >> 2;
    int n = nt * 16 + (lane & 15);          // 0..767 across layers
    int k = ks * 32 + (lane >> 4) * 8;
    int l = n >> 8; int c = n & 255; int h = c >> 5, bk = c & 31;
    const float* e = emb + ((size_t)l * NBUK + bk) * DM + h * DK;
    const float* wq = Wq + ((size_t)l * DM + h * DK) * DM;
    u16* ph = PH + (size_t)idx * 8;
    u16* pl = PL + (size_t)idx * 8;
    #pragma unroll
    for (int q = 0; q < 8; ++q) {
      float s = 0.f;
      #pragma unroll
      for (int d = 0; d < DK; ++d) s += e[d] * wq[(size_t)d * DM + k + q];
      u16 hh = f2bf(s);
      ph[q] = hh;
      pl[q] = f2bf(s - bf2f(hh));
    }
    return;
  }
  const float* W; int rel, Kdim;
  if (idx < 24576) {
    int seg = idx / 6144; rel = idx % 6144; Kdim = 128;
    W = seg == 0 ? Wq : seg == 1 ? Wk : seg == 2 ? Wv : Wo;
  } else if (idx < 49152) { rel = idx - 24576; Kdim = 128; W = W1; }
  else if (idx < 73728)   { rel = idx - 49152; Kdim = 512; W = W2; }
  else                    { rel = idx - 73728; Kdim = 128; W = oW; }
  int lane = rel & 63;
  int g = rel >> 6;
  int ksteps = Kdim >> 5;
  int ks = g % ksteps, nt = g / ksteps;
  int n = nt * 16 + (lane & 15);
  int k = ks * 32 + (lane >> 4) * 8;
  const float* p = W + (size_t)n * Kdim + k;
  u16* ph = PH + (size_t)idx * 8;
  u16* pl = PL + (size_t)idx * 8;
  #pragma unroll
  for (int q = 0; q < 8; ++q) {
    float x = p[q];
    u16 hh = f2bf(x);
    ph[q] = hh;
    pl[q] = f2bf(x - bf2f(hh));
  }
}

// ---------------------------------------------------------------- embed (+g row inline)
// node blocks cover b,n<NN,d; last BB blocks compute g = gnode + inb + mean(coords)@inW^T
#define NBNODE 1024    // ceil(BB*NN*DM/256)
__global__ void embed_kernel(const float* __restrict__ coords, const float* __restrict__ inW,
                             const float* __restrict__ inb, const float* __restrict__ gnode,
                             float* __restrict__ X) {
  if (blockIdx.x >= NBNODE) {
    int b = blockIdx.x - NBNODE;
    int t = threadIdx.x;
    if (t >= 128) return;
    int lane = t & 63;
    float sx = 0.f, sy = 0.f;
    for (int n = lane; n < NN; n += 64) {
      float2 c = *(const float2*)(coords + (size_t)(b * NN + n) * 2);
      sx += c.x; sy += c.y;
    }
    #pragma unroll
    for (int o = 1; o < 64; o <<= 1) { sx += __shfl_xor(sx, o); sy += __shfl_xor(sy, o); }
    float mx = sx * (1.0f / NN), my = sy * (1.0f / NN);
    int d = t;   // 0..127
    X[((size_t)b * N1 + NN) * DM + d] =
        gnode[d] + inb[d] + mx * inW[d * 2 + 0] + my * inW[d * 2 + 1];
    return;
  }
  int idx = blockIdx.x * 256 + threadIdx.x;
  if (idx >= BB * NN * DM) return;
  int d = idx % DM; int r = idx / DM; int n = r % NN; int b = r / NN;
  float cx = coords[(b * NN + n) * 2 + 0], cy = coords[(b * NN + n) * 2 + 1];
  X[((size_t)b * N1 + n) * DM + d] = cx * inW[d * 2 + 0] + cy * inW[d * 2 + 1] + inb[d];
}

// ---------------------------------------------------------------- bucket (padded rows)
__global__ void bucket_kernel(const float* __restrict__ coords, unsigned char* __restrict__ buckp) {
  int idx = blockIdx.x * 256 + threadIdx.x;
  if (idx >= BB * N1 * BSTR) return;
  int j = idx % BSTR; int r = idx / BSTR; int i = r % N1; int b = r / N1;
  unsigned char v = 0;
  if (j < N1) {
    float xi = 0.f, yi = 0.f, xj = 0.f, yj = 0.f;
    if (i < NN) { xi = coords[(b * NN + i) * 2]; yi = coords[(b * NN + i) * 2 + 1]; }
    if (j < NN) { xj = coords[(b * NN + j) * 2]; yj = coords[(b * NN + j) * 2 + 1]; }
    float dx = xi - xj, dy = yi - yj;
    float dist = sqrtf(dx * dx + dy * dy);
    int bu = (int)(dist * 32.0f);
    bu = bu < 0 ? 0 : (bu > 31 ? 31 : bu);
    v = (unsigned char)bu;
  }
  buckp[idx] = v;
}

// ---------------------------------------------------------------- X split (3-level exact) + rowsq + adj zero
__global__ __launch_bounds__(256) void xsplit_kernel(
    const float* __restrict__ X, u16* __restrict__ XH, u16* __restrict__ XM,
    u16* __restrict__ XL, float* __restrict__ sqb, unsigned long long* __restrict__ adj) {
  int t = threadIdx.x;
  int tid = blockIdx.x * 256 + t;
  if (tid < BB * N1 * ADJW) adj[tid] = 0ull;      // 513*256 = 131328 >= 34850
  int wave = blockIdx.x * 4 + (t >> 6), lane = t & 63;
  if (wave >= BB * N1) return;
  float2 v = *(const float2*)(X + (size_t)wave * DM + lane * 2);
  u16 h0 = f2bf(v.x); float r1 = v.x - bf2f(h0);
  u16 m0 = f2bf(r1);  u16 l0 = f2bf(r1 - bf2f(m0));
  u16 h1 = f2bf(v.y); float r2 = v.y - bf2f(h1);
  u16 m1 = f2bf(r2);  u16 l1 = f2bf(r2 - bf2f(m1));
  size_t o = (size_t)wave * DM + lane * 2;
  *(u32*)&XH[o] = (u32)h0 | ((u32)h1 << 16);
  *(u32*)&XM[o] = (u32)m0 | ((u32)m1 << 16);
  *(u32*)&XL[o] = (u32)l0 | ((u32)l1 << 16);
  float sq = v.x * v.x + v.y * v.y;
  #pragma unroll
  for (int oo = 1; oo < 64; oo <<= 1) sq += __shfl_xor(sq, oo);
  if (lane == 0) {
    int b = wave / N1, n = wave % N1;
    if (n < NN) sqb[b * NN + n] = sq;
  }
}

// ---------------------------------------------------------------- exact MFMA gram (3-level, prestaged)
__global__ __launch_bounds__(256) void gram_kernel(
    const u16* __restrict__ XH, const u16* __restrict__ XM, const u16* __restrict__ XL,
    const float* __restrict__ sqb, float* __restrict__ d2) {
  __shared__ __align__(16) u16 AsH[32][72];
  __shared__ __align__(16) u16 AsM[32][72];
  __shared__ __align__(16) u16 AsL[32][72];
  __shared__ __align__(16) u16 BsH[64][72];
  __shared__ __align__(16) u16 BsM[64][72];
  __shared__ __align__(16) u16 BsL[64][72];
  int b = blockIdx.z;
  int m0 = blockIdx.x * 32, n0 = blockIdx.y * 64;
  size_t boff = (size_t)b * N1;
  int t = threadIdx.x;
  int lane = t & 63, w = t >> 6;
  int wm = (w >> 1) * 16, wn = (w & 1) * 32;
  int quad = lane >> 4, r16 = lane & 15;

  f4 acc0 = {0.f, 0.f, 0.f, 0.f}, acc1 = {0.f, 0.f, 0.f, 0.f};
  int ar = t >> 3, as_ = (t & 7) * 8;     // A: 32 rows x 8 segs of 8
  int br = t >> 2, bs_ = (t & 3) * 16;    // B: 64 rows x 4 segs of 16

  for (int k0 = 0; k0 < DM; k0 += 64) {
    {
      size_t src = (boff + m0 + ar) * DM + k0 + as_;
      *(bf8*)&AsH[ar][as_] = *(const bf8*)(XH + src);
      *(bf8*)&AsM[ar][as_] = *(const bf8*)(XM + src);
      *(bf8*)&AsL[ar][as_] = *(const bf8*)(XL + src);
    }
    {
      size_t src = (boff + n0 + br) * DM + k0 + bs_;
      *(bf8*)&BsH[br][bs_] = *(const bf8*)(XH + src);
      *(bf8*)&BsH[br][bs_ + 8] = *(const bf8*)(XH + src + 8);
      *(bf8*)&BsM[br][bs_] = *(const bf8*)(XM + src);
      *(bf8*)&BsM[br][bs_ + 8] = *(const bf8*)(XM + src + 8);
      *(bf8*)&BsL[br][bs_] = *(const bf8*)(XL + src);
      *(bf8*)&BsL[br][bs_ + 8] = *(const bf8*)(XL + src + 8);
    }
    __syncthreads();
    #pragma unroll
    for (int ks = 0; ks < 64; ks += 16) {
      int seg = (quad & 1) * 8;
      bf8 aHM = *(const bf8*)((quad < 2) ? &AsH[wm + r16][ks + seg] : &AsM[wm + r16][ks + seg]);
      bf8 aHL = *(const bf8*)((quad < 2) ? &AsH[wm + r16][ks + seg] : &AsL[wm + r16][ks + seg]);
      #pragma unroll
      for (int tt = 0; tt < 2; ++tt) {
        int nr = wn + tt * 16 + r16;
        bf8 bH = *(const bf8*)&BsH[nr][ks + seg];
        bf8 bM = *(const bf8*)&BsM[nr][ks + seg];
        bf8 b3 = *(const bf8*)((quad < 2) ? &BsL[nr][ks + seg] : &BsH[nr][ks + seg]);
        f4& a = tt ? acc1 : acc0;
        a = __builtin_amdgcn_mfma_f32_16x16x32_bf16(aHM, bH, a, 0, 0, 0);  // HH' + MH'
        a = __builtin_amdgcn_mfma_f32_16x16x32_bf16(aHM, bM, a, 0, 0, 0);  // HM' + MM'
        a = __builtin_amdgcn_mfma_f32_16x16x32_bf16(aHL, b3, a, 0, 0, 0);  // HL' + LH'
      }
    }
    __syncthreads();
  }

  #pragma unroll
  for (int tt = 0; tt < 2; ++tt) {
    f4 a = tt ? acc1 : acc0;
    int n = n0 + wn + tt * 16 + r16;
    float sj = sqb[b * NN + n];
    #pragma unroll
    for (int reg = 0; reg < 4; ++reg) {
      int m = m0 + wm + quad * 4 + reg;
      float si = sqb[b * NN + m];
      float v = (m == n) ? BIGF : (si + sj - 2.f * a[reg]);
      d2[((size_t)b * NN + m) * NN + n] = v;
    }
  }
}

// ---------------------------------------------------------------- top-10 select -> adjacency bits
__global__ __launch_bounds__(256) void knnsel_kernel(const float* __restrict__ d2,
                                                     unsigned long long* __restrict__ adj) {
  __shared__ float dd[4][NN];
  int blk = blockIdx.x;
  int b = blk / (NN / 4);
  int i0 = (blk % (NN / 4)) * 4;
  int t = threadIdx.x, lane = t & 63, w = t >> 6;

  const float4* src = (const float4*)(d2 + ((size_t)b * NN + i0) * NN);
  float4* dst = (float4*)&dd[0][0];
  #pragma unroll
  for (int x = 0; x < 4; ++x) dst[t + x * 256] = src[t + x * 256];
  __syncthreads();

  int i = i0 + w;
  for (int it = 0; it < KNN_K; ++it) {
    float bv = BIGF; int bi = 0x3fffffff;
    for (int j = lane; j < NN; j += 64) {
      float v = dd[w][j];
      if (v < bv) { bv = v; bi = j; }
    }
    #pragma unroll
    for (int o = 1; o < 64; o <<= 1) {
      float ov = __shfl_xor(bv, o); int oi = __shfl_xor(bi, o);
      if (ov < bv || (ov == bv && oi < bi)) { bv = ov; bi = oi; }
    }
    if (lane == 0) {
      dd[w][bi] = BIGF;
      atomicOr(&adj[((size_t)b * N1 + i) * ADJW + (bi >> 6)], 1ull << (bi & 63));
      atomicOr(&adj[((size_t)b * N1 + bi) * ADJW + (i >> 6)], 1ull << (i & 63));
    }
  }
}

// ---------------------------------------------------------------- direct-fragment GEMM (16x16/wave)
__device__ __forceinline__ void gemm_dev16(
    const u16* __restrict__ AH, const u16* __restrict__ AL,
    const u16* __restrict__ PH, const u16* __restrict__ PL,
    const float* __restrict__ bias, const float* __restrict__ res,
    float* __restrict__ outF, u16* __restrict__ outH, u16* __restrict__ outL,
    int M, int Kdim, int Nout, int relu, int mt, int nt) {
  int lane = threadIdx.x & 63;
  int quad = lane >> 4, r16 = lane & 15;
  int ksteps = Kdim >> 5;
  f4 acc = {0.f, 0.f, 0.f, 0.f};

  int m0 = mt * 16;
  int mrow = m0 + r16; if (mrow >= M) mrow = M - 1;   // clamp; result discarded
  const u16* aph = AH + (size_t)mrow * Kdim + quad * 8;
  const u16* apl = AL + (size_t)mrow * Kdim + quad * 8;
  const u16* ph = PH + ((size_t)nt * ksteps * 64 + lane) * 8;
  const u16* pl = PL + ((size_t)nt * ksteps * 64 + lane) * 8;

  #pragma unroll 4
  for (int ks = 0; ks < ksteps; ++ks) {
    bf8 aH = *(const bf8*)(aph);
    bf8 aL = *(const bf8*)(apl);
    aph += 32; apl += 32;
    bf8 bH = *(const bf8*)(ph + (size_t)ks * 512);
    bf8 bL = *(const bf8*)(pl + (size_t)ks * 512);
    acc = __builtin_amdgcn_mfma_f32_16x16x32_bf16(aH, bH, acc, 0, 0, 0);
    acc = __builtin_amdgcn_mfma_f32_16x16x32_bf16(aH, bL, acc, 0, 0, 0);
    acc = __builtin_amdgcn_mfma_f32_16x16x32_bf16(aL, bH, acc, 0, 0, 0);
  }

  if (m0 >= M) return;
  int n = nt * 16 + r16;
  #pragma unroll
  for (int reg = 0; reg < 4; ++reg) {
    int m = m0 + quad * 4 + reg;    // C layout: col=lane&15, row=quad*4+reg
    if (m < M) {
      float v = acc[reg];
      if (bias) v += bias[n];
      if (relu) v = fmaxf(v, 0.f);
      if (res) v += res[(size_t)m * Nout + n];
      size_t oi = (size_t)m * Nout + n;
      if (outF) outF[oi] = v;
      if (outH) {
        u16 hh = f2bf(v);
        outH[oi] = hh;
        outL[oi] = f2bf(v - bf2f(hh));
      }
    }
  }
}

__global__ __launch_bounds__(256) void gemm_kernel(
    const u16* __restrict__ AH, const u16* __restrict__ AL,
    const u16* __restrict__ PH, const u16* __restrict__ PL,
    const float* __restrict__ bias, const float* __restrict__ res,
    float* __restrict__ outF, u16* __restrict__ outH, u16* __restrict__ outL,
    int M, int Kdim, int Nout, int relu) {
  gemm_dev16(AH, AL, PH, PL, bias, res, outF, outH, outL, M, Kdim, Nout, relu,
             blockIdx.x * 4 + (threadIdx.x >> 6), blockIdx.y);
}

// QKV+QE flattened grid: y<8 Q (0.25-scaled split), <16 K (split), <24 V (bf16), <40 qe (fp32)
__global__ __launch_bounds__(256) void gemm_qkv_kernel(
    const u16* __restrict__ AH, const u16* __restrict__ AL,
    const u16* __restrict__ Pbase_H, const u16* __restrict__ Pbase_L,
    size_t offQ, size_t offK, size_t offV, size_t offE,
    u16* __restrict__ QH, u16* __restrict__ QL,
    u16* __restrict__ KH, u16* __restrict__ KL, u16* __restrict__ Vbf,
    float* __restrict__ qe_all, int M) {
  int y = blockIdx.y;
  int z, nt;
  if (y < 8) { z = 0; nt = y; }
  else if (y < 16) { z = 1; nt = y - 8; }
  else if (y < 24) { z = 2; nt = y - 16; }
  else { z = 3; nt = y - 24; }
  size_t woff = z == 0 ? offQ : (z == 1 ? offK : (z == 2 ? offV : offE));
  const u16* PH = Pbase_H + woff;
  const u16* PL = Pbase_L + woff;
  int lane = threadIdx.x & 63;
  int quad = lane >> 4, r16 = lane & 15;
  int mt = blockIdx.x * 4 + (threadIdx.x >> 6);
  f4 acc = {0.f, 0.f, 0.f, 0.f};
  int m0 = mt * 16;
  int mrow = m0 + r16; if (mrow >= M) mrow = M - 1;
  const u16* aph = AH + (size_t)mrow * DM + quad * 8;
  const u16* apl = AL + (size_t)mrow * DM + quad * 8;
  const u16* ph = PH + ((size_t)nt * 4 * 64 + lane) * 8;
  const u16* pl = PL + ((size_t)nt * 4 * 64 + lane) * 8;
  #pragma unroll
  for (int ks = 0; ks < 4; ++ks) {
    bf8 aH = *(const bf8*)(aph);
    bf8 aL = *(const bf8*)(apl);
    aph += 32; apl += 32;
    bf8 bH = *(const bf8*)(ph + (size_t)ks * 512);
    bf8 bL = *(const bf8*)(pl + (size_t)ks * 512);
    acc = __builtin_amdgcn_mfma_f32_16x16x32_bf16(aH, bH, acc, 0, 0, 0);
    acc = __builtin_amdgcn_mfma_f32_16x16x32_bf16(aH, bL, acc, 0, 0, 0);
    acc = __builtin_amdgcn_mfma_f32_16x16x32_bf16(aL, bH, acc, 0, 0, 0);
  }
  if (m0 >= M) return;
  int n = nt * 16 + r16;
  #pragma unroll
  for (int reg = 0; reg < 4; ++reg) {
    int m = m0 + quad * 4 + reg;
    if (m >= M) continue;
    float v = acc[reg];
    if (z == 3) {
      int b = m / N1, nr = m % N1;
      int h = n >> 5, bk = n & 31;
      qe_all[(((size_t)b * NH + h) * N1 + nr) * 32 + bk] = v;
      continue;
    }
    size_t oi = (size_t)m * DM + n;
    if (z == 0) {
      float sv = v * 0.25f;
      u16 hh = f2bf(sv);
      QH[oi] = hh;
      QL[oi] = f2bf(sv - bf2f(hh));
    } else if (z == 1) {
      u16 hh = f2bf(v);
      KH[oi] = hh;
      KL[oi] = f2bf(v - bf2f(hh));
    } else {
      Vbf[oi] = f2bf(v);
    }
  }
}

// ---------------------------------------------------------------- MFMA flash attention, key-split
// Fixed-offset softmax; mask words computed inline from adj + static band/depot/diag.
#define CH 64
#define NCH 17
__global__ __launch_bounds__(128) void attn_kernel(
    const u16* __restrict__ QH, const u16* __restrict__ QL,
    const u16* __restrict__ KH, const u16* __restrict__ KL,
    const u16* __restrict__ Vbf, const float* __restrict__ qe_all,
    const unsigned char* __restrict__ buckp, const unsigned long long* __restrict__ adj,
    float* __restrict__ Opart, float* __restrict__ lpart) {
  __shared__ __align__(16) u16 KsHi[2][CH][20];
  __shared__ __align__(16) u16 KsLo[2][CH][20];
  __shared__ __align__(16) u16 Vt[2][DK][68];
  __shared__ __align__(16) u16 Ps[2][16][72];
  __shared__ __align__(16) float qe_s[2][16][36];
  __shared__ u32 maskS[32][6];
  __shared__ unsigned char buckS[2][32][68];

  int qt = blockIdx.x;
  int h = blockIdx.y & 7, b = blockIdx.y >> 3;
  int s = blockIdx.z;
  int c0 = (NCH * s) / NSPLIT, c1 = (NCH * (s + 1)) / NSPLIT;
  int nwm = 2 * (c1 - c0);
  int t = threadIdx.x, lane = t & 63, w = t >> 6;
  int quad = lane >> 4, r16 = lane & 15;
  int i0 = qt * 32;
  int iw = i0 + w * 16;
  int bh = b * NH + h;

  // mask words inline (== old connb_kernel output, bit-exact)
  for (int x = t; x < 32 * nwm; x += 128) {
    int rr = x / nwm, ww = x % nwm;
    int gi = i0 + rr; if (gi > NN) gi = NN;
    int W = 2 * c0 + ww;
    u32 v;
    if (gi == 0 || gi == NN) {
      v = 0xffffffffu;
    } else {
      const u32* a32 = (const u32*)(adj + ((size_t)b * N1 + gi) * ADJW);
      v = a32[W];
      int bs = gi & ~127;
      int lo = gi - 11 < bs ? bs : gi - 11;
      int be = bs + 127;
      int hi = gi + 11 > be ? be : gi + 11;
      int aa = lo - 32 * W, bnd = hi - 32 * W;
      if (aa < 0) aa = 0; if (bnd > 31) bnd = 31;
      if (aa <= bnd) v |= (0xffffffffu << aa) & (0xffffffffu >> (31 - bnd));
      if (W == 0) v |= 1u;
      if (W == 32) v |= 1u;
      int dg = gi - 32 * W;
      if (dg >= 0 && dg < 32) v |= 1u << dg;
    }
    if (W == 32) v &= 1u;
    else if (W == 33) v = 0u;
    maskS[rr][ww] = v;
  }
  // qe table: per-row clamped load
  #pragma unroll
  for (int e = 0; e < 2; ++e) {
    int x = lane + e * 64;
    int rr = x >> 3, bk = (x & 7) * 4;
    int gi = iw + rr; if (gi > NN) gi = NN;
    f4 v = *(const f4*)(qe_all + (((size_t)b * NH + h) * N1 + gi) * 32 + bk);
    *(f4*)&qe_s[w][rr][bk] = v;
  }
  bf8 qfrag;
  {
    int gi = iw + r16; if (gi > NN) gi = NN;
    const u16* qsrc = (quad < 2 ? QH : QL) + ((size_t)(b * N1 + gi) * DM + h * DK + (quad & 1) * 8);
    qfrag = *(const bf8*)qsrc;
  }

  ushort4 khr[2], klr[2], vvr[2]; u32 bkr[4];
  auto load_chunk = [&](int c) {
    int j0 = c * CH;
    #pragma unroll
    for (int ii = 0; ii < 2; ++ii) {
      int x = t + ii * 128;
      int key = x >> 2, ds = (x & 3) * 4;
      int jg = j0 + key; if (jg > NN) jg = NN;
      size_t src = (size_t)(b * N1 + jg) * DM + h * DK + ds;
      khr[ii] = *(const ushort4*)(KH + src);
      klr[ii] = *(const ushort4*)(KL + src);
      vvr[ii] = *(const ushort4*)(Vbf + src);
    }
    #pragma unroll
    for (int ii = 0; ii < 4; ++ii) {
      int x = t + ii * 128;
      int rr = x >> 4, c4 = (x & 15) * 4;
      int gi = i0 + rr; if (gi > NN) gi = NN;
      bkr[ii] = *(const u32*)(buckp + ((size_t)b * N1 + gi) * BSTR + j0 + c4);
    }
  };
  auto store_chunk = [&](int pb) {
    #pragma unroll
    for (int ii = 0; ii < 2; ++ii) {
      int x = t + ii * 128;
      int key = x >> 2, ds = (x & 3) * 4;
      *(ushort4*)&KsHi[pb][key][ds] = khr[ii];
      *(ushort4*)&KsLo[pb][key][ds] = klr[ii];
      Vt[pb][ds + 0][key] = vvr[ii].x;
      Vt[pb][ds + 1][key] = vvr[ii].y;
      Vt[pb][ds + 2][key] = vvr[ii].z;
      Vt[pb][ds + 3][key] = vvr[ii].w;
    }
    #pragma unroll
    for (int ii = 0; ii < 4; ++ii) {
      int x = t + ii * 128;
      int rr = x >> 4, c4 = (x & 15) * 4;
      *(u32*)&buckS[pb][rr][c4] = bkr[ii];
    }
  };

  f4 Oacc = {0.f, 0.f, 0.f, 0.f};
  float lrun[4] = {0.f, 0.f, 0.f, 0.f};

  load_chunk(c0);
  store_chunk(0);

  for (int c = c0; c < c1; ++c) {
    int pb = (c - c0) & 1;
    bool pf = (c + 1 < c1);
    if (pf) load_chunk(c + 1);
    __syncthreads();

    f4 S[4];
    #pragma unroll
    for (int tt = 0; tt < 4; ++tt) {
      int key = tt * 16 + r16;
      int off = (quad & 1) * 8;
      bf8 bhv = mk8(*(const ushort4*)&KsHi[pb][key][off], *(const ushort4*)&KsHi[pb][key][off + 4]);
      bf8 blv = mk8(*(const ushort4*)&KsLo[pb][key][off], *(const ushort4*)&KsLo[pb][key][off + 4]);
      f4 z = {0.f, 0.f, 0.f, 0.f};
      z = __builtin_amdgcn_mfma_f32_16x16x32_bf16(qfrag, bhv, z, 0, 0, 0);
      z = __builtin_amdgcn_mfma_f32_16x16x32_bf16(qfrag, blv, z, 0, 0, 0);
      S[tt] = z;
    }

    #pragma unroll
    for (int rg = 0; rg < 4; ++rg) {
      int rowb = w * 16 + quad * 4 + rg;
      u32 mw0 = maskS[rowb][2 * (c - c0)];
      u32 mw1 = maskS[rowb][2 * (c - c0) + 1];
      float ps = 0.f;
      #pragma unroll
      for (int tt = 0; tt < 4; ++tt) {
        u32 mword = (tt & 2) ? mw1 : mw0;
        int bit = (tt & 1) * 16 + r16;
        int bk = buckS[pb][rowb][tt * 16 + r16] & 31;
        float rel = qe_s[w][quad * 4 + rg][bk];
        float sc = S[tt][rg] + rel;
        sc += ((mword >> bit) & 1u) ? 0.f : -1.0e9f;
        float p = __expf(sc - SM_OFF);
        ps += p;
        Ps[w][quad * 4 + rg][tt * 16 + r16] = f2bf(p);
      }
      #pragma unroll
      for (int o = 1; o < 16; o <<= 1) ps += __shfl_xor(ps, o);
      lrun[rg] += ps;
    }
    #pragma unroll
    for (int half = 0; half < 2; ++half) {
      bf8 pa = *(const bf8*)&Ps[w][r16][half * 32 + quad * 8];
      bf8 vb = mk8(*(const ushort4*)&Vt[pb][r16][half * 32 + quad * 8],
                   *(const ushort4*)&Vt[pb][r16][half * 32 + quad * 8 + 4]);
      Oacc = __builtin_amdgcn_mfma_f32_16x16x32_bf16(pa, vb, Oacc, 0, 0, 0);
    }

    if (pf) store_chunk(pb ^ 1);
  }

  #pragma unroll
  for (int rg = 0; rg < 4; ++rg) {
    int gi = i0 + w * 16 + quad * 4 + rg;
    if (gi < N1) {
      size_t base = ((size_t)(bh * NSPLIT + s) * N1 + gi);
      Opart[base * 16 + r16] = Oacc[rg];
      if (r16 == 0) lpart[base] = lrun[rg];
    }
  }
}

// ---------------------------------------------------------------- combine split partials (plain sums)
__global__ void attn_combine_kernel(const float* __restrict__ Opart,
                                    const float* __restrict__ lpart,
                                    u16* __restrict__ CbH, u16* __restrict__ CbL) {
  int idx = blockIdx.x * 256 + threadIdx.x;
  if (idx >= BB * NH * N1) return;
  int q = idx % N1; int bh = idx / N1; int h = bh & 7; int b = bh >> 3;
  float l = 0.f;
  float o[16];
  #pragma unroll
  for (int d = 0; d < DK; ++d) o[d] = 0.f;
  #pragma unroll
  for (int s = 0; s < NSPLIT; ++s) {
    size_t base = (size_t)(bh * NSPLIT + s) * N1 + q;
    l += lpart[base];
    const float* op = Opart + base * 16;
    #pragma unroll
    for (int d = 0; d < DK; ++d) o[d] += op[d];
  }
  float inv = 1.0f / l;
  size_t obase = ((size_t)b * N1 + q) * DM + h * DK;
  #pragma unroll
  for (int d = 0; d < DK; ++d) {
    float v = o[d] * inv;
    u16 hh = f2bf(v);
    CbH[obase + d] = hh;
    CbL[obase + d] = f2bf(v - bf2f(hh));
  }
}

// ---------------------------------------------------------------- instance norm (+pool/g, +split emit)
__global__ void inorm_kernel(float* __restrict__ X, const float* __restrict__ w,
                             const float* __restrict__ b_, float* __restrict__ pool,
                             int do_g, u16* __restrict__ oH, u16* __restrict__ oL) {
  int d = blockIdx.x; int bb = blockIdx.y; int lane = threadIdx.x;
  float g_old = X[((size_t)bb * N1 + NN) * DM + d];
  float s = 0.f;
  for (int n = lane; n < N1; n += 64) s += X[((size_t)bb * N1 + n) * DM + d];
  #pragma unroll
  for (int o = 1; o < 64; o <<= 1) s += __shfl_xor(s, o);
  float mu = s * (1.0f / N1);
  float v = 0.f;
  for (int n = lane; n < N1; n += 64) {
    float tt = X[((size_t)bb * N1 + n) * DM + d] - mu;
    v += tt * tt;
  }
  #pragma unroll
  for (int o = 1; o < 64; o <<= 1) v += __shfl_xor(v, o);
  float var = v * (1.0f / N1);
  float scv = rsqrtf(var + 1e-5f) * w[d];
  float sh = b_[d];
  for (int n = lane; n < N1; n += 64) {
    size_t id = ((size_t)bb * N1 + n) * DM + d;
    float nv = (X[id] - mu) * scv + sh;
    X[id] = nv;
    if (oH) {
      u16 hh = f2bf(nv);
      oH[id] = hh;
      oL[id] = f2bf(nv - bf2f(hh));
    }
  }
  if (lane == 0) {
    float hmean = ((s - g_old) * (1.0f / NN) - mu) * scv + sh;
    if (pool) pool[bb * DM + d] = hmean;
    if (do_g) X[((size_t)bb * N1 + NN) * DM + d] += hmean;
  }
}

// ---------------------------------------------------------------- final GEMM (inline h+pm split, +out_pm)
__global__ __launch_bounds__(256) void gemm_final_kernel(
    const float* __restrict__ X, const float* __restrict__ pools,
    const u16* __restrict__ PH, const u16* __restrict__ PL,
    const float* __restrict__ bias, float* __restrict__ out, float* __restrict__ out_pm) {
  int t = threadIdx.x;
  if (blockIdx.x == 0 && blockIdx.y == 0) {
    // out_pm: 256 values (b,d)
    float pmv = (pools[t] + pools[BB * DM + t] + pools[2 * BB * DM + t]) * (1.0f / 3.0f);
    out_pm[t] = pmv;
  }
  int lane = t & 63;
  int quad = lane >> 4, r16 = lane & 15;
  int mt = blockIdx.x * 4 + (t >> 6), nt = blockIdx.y;
  const int M = BB * NN;
  f4 acc = {0.f, 0.f, 0.f, 0.f};
  int m0 = mt * 16;
  int mrow = m0 + r16; if (mrow >= M) mrow = M - 1;
  int mb = mrow / NN, mn = mrow % NN;
  const float* xp = X + ((size_t)mb * N1 + mn) * DM + quad * 8;
  const float* pp = pools + mb * DM + quad * 8;
  const u16* ph = PH + ((size_t)nt * 4 * 64 + lane) * 8;
  const u16* pl = PL + ((size_t)nt * 4 * 64 + lane) * 8;
  #pragma unroll
  for (int ks = 0; ks < 4; ++ks) {
    bf8 aH, aL;
    #pragma unroll
    for (int half = 0; half < 2; ++half) {
      float4 xv = *(const float4*)(xp + ks * 32 + half * 4);
      float4 p0 = *(const float4*)(pp + ks * 32 + half * 4);
      float4 p1 = *(const float4*)(pp + BB * DM + ks * 32 + half * 4);
      float4 p2 = *(const float4*)(pp + 2 * BB * DM + ks * 32 + half * 4);
      float av[4] = {xv.x + (p0.x + p1.x + p2.x) * (1.0f / 3.0f),
                     xv.y + (p0.y + p1.y + p2.y) * (1.0f / 3.0f),
                     xv.z + (p0.z + p1.z + p2.z) * (1.0f / 3.0f),
                     xv.w + (p0.w + p1.w + p2.w) * (1.0f / 3.0f)};
      #pragma unroll
      for (int q = 0; q < 4; ++q) {
        u16 hh = f2bf(av[q]);
        aH[half * 4 + q] = (short)hh;
        aL[half * 4 + q] = (short)f2bf(av[q] - bf2f(hh));
      }
    }
    bf8 bH = *(const bf8*)(ph + (size_t)ks * 512);
    bf8 bL = *(const bf8*)(pl + (size_t)ks * 512);
    acc = __builtin_amdgcn_mfma_f32_16x16x32_bf16(aH, bH, acc, 0, 0, 0);
    acc = __builtin_amdgcn_mfma_f32_16x16x32_bf16(aH, bL, acc, 0, 0, 0);
    acc = __builtin_amdgcn_mfma_f32_16x16x32_bf16(aL, bH, acc, 0, 0, 0);
  }
  int n = nt * 16 + r16;
  #pragma unroll
  for (int reg = 0; reg < 4; ++reg) {
    int m = m0 + quad * 4 + reg;
    if (m < M) out[(size_t)m * DM + n] = acc[reg] + bias[n];
  }
}

// ================================================================ launch
extern "C" void kernel_launch(void* const* d_in, const int* in_sizes, int n_in,
                              void* d_out, int out_size, void* d_ws, size_t ws_size,
                              hipStream_t stream) {
  const float* coords = (const float*)d_in[0];
  const float* inW    = (const float*)d_in[1];
  const float* inb    = (const float*)d_in[2];
  const float* gnode  = (const float*)d_in[3];
  const float* Wq     = (const float*)d_in[4];
  const float* Wk     = (const float*)d_in[5];
  const float* Wv     = (const float*)d_in[6];
  const float* Wo     = (const float*)d_in[7];
  const float* emb    = (const float*)d_in[8];
  const float* W1     = (const float*)d_in[9];
  const float* b1     = (const float*)d_in[10];
  const float* W2     = (const float*)d_in[11];
  const float* b2     = (const float*)d_in[12];
  const float* n1w    = (const float*)d_in[13];
  const float* n1b    = (const float*)d_in[14];
  const float* n2w    = (const float*)d_in[15];
  const float* n2b    = (const float*)d_in[16];
  const float* outW   = (const float*)d_in[17];
  const float* outb   = (const float*)d_in[18];
  float* out = (float*)d_out;

  char* wsp = (char*)d_ws;
  size_t off = 0;
  auto alloc = [&](size_t bytes) -> void* {
    off = (off + 255) & ~(size_t)255;
    void* p = wsp + off;
    off += bytes;
    return p;
  };
  const size_t XB = (size_t)BB * N1 * DM * 4;       // fp32 activation buffer
  const size_t HB = (size_t)BB * N1 * DM * 2;       // u16 half buffer
  float* X0   = (float*)alloc(XB);
  float* X1   = (float*)alloc(XB);
  float* Yb   = (float*)alloc(XB);
  u16* XH = (u16*)alloc(HB); u16* XM = (u16*)alloc(HB); u16* XL = (u16*)alloc(HB);
  u16* QH = (u16*)alloc(HB); u16* QL = (u16*)alloc(HB);
  u16* KH = (u16*)alloc(HB); u16* KL = (u16*)alloc(HB);
  u16* Vbf = (u16*)alloc(HB);
  u16* CbH = (u16*)alloc(HB); u16* CbL = (u16*)alloc(HB);
  u16* YbH = (u16*)alloc(HB); u16* YbL = (u16*)alloc(HB);
  u16* FbH = (u16*)alloc((size_t)BB * N1 * DFF * 2);
  u16* FbL = (u16*)alloc((size_t)BB * N1 * DFF * 2);
  unsigned char* buckp = (unsigned char*)alloc((size_t)BB * N1 * BSTR);
  unsigned long long* adj = (unsigned long long*)alloc((size_t)BB * N1 * ADJW * 8);
  float* sqb   = (float*)alloc((size_t)BB * NN * 4);
  float* pools = (float*)alloc((size_t)NLAYERS * BB * DM * 4);
  float* qe_all = (float*)alloc((size_t)BB * NH * N1 * 32 * 4);
  float* lpart = (float*)alloc((size_t)BB * NH * NSPLIT * N1 * 4);
  u16* PH = (u16*)alloc((size_t)PW_TOT * 2);
  u16* PL = (u16*)alloc((size_t)PW_TOT * 2);
  float* scratch8 = (float*)alloc((size_t)BB * NH * NSPLIT * N1 * 16 * 4);  // >= d2 size

  float* d2 = scratch8;                    // gram keys (8.39 MB), dead before attn
  float* Opart = scratch8;                 // attn partials (8.40 MB)

  prepack_kernel<<<(88064 + 255) / 256, 256, 0, stream>>>(Wq, Wk, Wv, Wo, W1, W2, outW, emb, PH, PL);
  embed_kernel<<<NBNODE + BB, 256, 0, stream>>>(coords, inW, inb, gnode, X0);
  bucket_kernel<<<(BB * N1 * BSTR + 255) / 256, 256, 0, stream>>>(coords, buckp);

  float* Xin = X0; float* Xout = X1;
  const int M = BB * N1;
  const int GX = 33;     // ceil(129 m-tiles / 4 waves)
  for (int l = 0; l < NLAYERS; ++l) {
    xsplit_kernel<<<513, 256, 0, stream>>>(Xin, XH, XM, XL, sqb, adj);
    gram_kernel<<<dim3(32, 16, BB), 256, 0, stream>>>(XH, XM, XL, sqb, d2);
    knnsel_kernel<<<BB * NN / 4, 256, 0, stream>>>(d2, adj);

    gemm_qkv_kernel<<<dim3(GX, 40), 256, 0, stream>>>(
        XH, XM, PH, PL,
        (size_t)PWQ_OFF + (size_t)l * DM * DM,
        (size_t)PWK_OFF + (size_t)l * DM * DM,
        (size_t)PWV_OFF + (size_t)l * DM * DM,
        (size_t)PWQE_OFF + (size_t)l * 256 * DM,
        QH, QL, KH, KL, Vbf, qe_all, M);

    attn_kernel<<<dim3(33, NH * BB, NSPLIT), 128, 0, stream>>>(
        QH, QL, KH, KL, Vbf, qe_all, buckp, adj, Opart, lpart);
    attn_combine_kernel<<<(BB * NH * N1 + 255) / 256, 256, 0, stream>>>(
        Opart, lpart, CbH, CbL);

    gemm_kernel<<<dim3(GX, 8), 256, 0, stream>>>(
        CbH, CbL, PH + PWO_OFF + (size_t)l * DM * DM, PL + PWO_OFF + (size_t)l * DM * DM,
        nullptr, Xin, Yb, nullptr, nullptr, M, DM, DM, 0);
    inorm_kernel<<<dim3(DM, BB), 64, 0, stream>>>(Yb, n1w + l * DM, n1b + l * DM,
                                                  nullptr, 0, YbH, YbL);

    gemm_kernel<<<dim3(GX, 32), 256, 0, stream>>>(
        YbH, YbL, PH + PW1_OFF + (size_t)l * DFF * DM, PL + PW1_OFF + (size_t)l * DFF * DM,
        b1 + l * DFF, nullptr, nullptr, FbH, FbL, M, DM, DFF, 1);
    gemm_kernel<<<dim3(GX, 8), 256, 0, stream>>>(
        FbH, FbL, PH + PW2_OFF + (size_t)l * DM * DFF, PL + PW2_OFF + (size_t)l * DM * DFF,
        b2 + l * DM, Yb, Xout, nullptr, nullptr, M, DFF, DM, 0);
    inorm_kernel<<<dim3(DM, BB), 64, 0, stream>>>(Xout, n2w + l * DM, n2b + l * DM,
                                                  pools + (size_t)l * BB * DM, 1,
                                                  nullptr, nullptr);

    float* t2 = Xin; Xin = Xout; Xout = t2;
  }

  gemm_final_kernel<<<dim3(32, 8), 256, 0, stream>>>(
      Xin, pools, PH + PWOUT_OFF, PL + PWOUT_OFF, outb, out, out + (size_t)BB * NN * DM);
}